// Round 1
// baseline (544.832 us; speedup 1.0000x reference)
//
#include <hip/hip_runtime.h>
#include <hip/hip_bf16.h>

#define SEQ 4096
#define HID 768
#define NHEAD 12
#define HDIM 64

typedef __attribute__((ext_vector_type(8))) short bf16x8;
typedef __attribute__((ext_vector_type(4))) float f32x4;

// fp32 -> bf16 (RNE), finite inputs only
static __device__ __forceinline__ short f2bf(float f) {
    unsigned u = __builtin_bit_cast(unsigned, f);
    unsigned r = (u + 0x7fffu + ((u >> 16) & 1u)) >> 16;
    return (short)r;
}

// ---------------------------------------------------------------------------
// Kernel 1: QKV projection. Y = X @ W^T + b for W in {Wq,Wk,Wv} (blockIdx.z).
// Outputs: Qb, Kb row-major bf16 [SEQ][HID]; Vt transposed bf16 [HID][SEQ]
// (row n = h*64+d), so attention PV B-fragments are contiguous.
// Block: 256 thr = 4 waves in 2x2, each wave a 32x32 tile (2x2 MFMA 16x16x32).
// ---------------------------------------------------------------------------
__global__ __launch_bounds__(256) void qkv_proj_kernel(
    const float* __restrict__ hs,
    const float* __restrict__ Wq, const float* __restrict__ bq,
    const float* __restrict__ Wk, const float* __restrict__ bk,
    const float* __restrict__ Wv, const float* __restrict__ bv,
    short* __restrict__ Qb, short* __restrict__ Kb, short* __restrict__ Vt)
{
    const int z = blockIdx.z;
    const float* __restrict__ W    = (z == 0) ? Wq : ((z == 1) ? Wk : Wv);
    const float* __restrict__ bias = (z == 0) ? bq : ((z == 1) ? bk : bv);

    const int lane = threadIdx.x & 63;
    const int w    = threadIdx.x >> 6;
    const int wm = w >> 1, wn = w & 1;
    const int m0 = blockIdx.y * 64 + wm * 32;
    const int n0 = blockIdx.x * 64 + wn * 32;
    const int lr  = lane & 15;         // row within 16 (A rows / B rows / C cols)
    const int lk8 = (lane >> 4) * 8;   // k offset for A/B fragments

    f32x4 acc[2][2] = {};

    for (int k0 = 0; k0 < HID; k0 += 32) {
        bf16x8 af[2], bfr[2];
#pragma unroll
        for (int im = 0; im < 2; ++im) {
            const float* src = hs + (size_t)(m0 + im * 16 + lr) * HID + k0 + lk8;
            float4 x0 = *reinterpret_cast<const float4*>(src);
            float4 x1 = *reinterpret_cast<const float4*>(src + 4);
            af[im][0] = f2bf(x0.x); af[im][1] = f2bf(x0.y);
            af[im][2] = f2bf(x0.z); af[im][3] = f2bf(x0.w);
            af[im][4] = f2bf(x1.x); af[im][5] = f2bf(x1.y);
            af[im][6] = f2bf(x1.z); af[im][7] = f2bf(x1.w);
        }
#pragma unroll
        for (int in_ = 0; in_ < 2; ++in_) {
            const float* src = W + (size_t)(n0 + in_ * 16 + lr) * HID + k0 + lk8;
            float4 x0 = *reinterpret_cast<const float4*>(src);
            float4 x1 = *reinterpret_cast<const float4*>(src + 4);
            bfr[in_][0] = f2bf(x0.x); bfr[in_][1] = f2bf(x0.y);
            bfr[in_][2] = f2bf(x0.z); bfr[in_][3] = f2bf(x0.w);
            bfr[in_][4] = f2bf(x1.x); bfr[in_][5] = f2bf(x1.y);
            bfr[in_][6] = f2bf(x1.z); bfr[in_][7] = f2bf(x1.w);
        }
#pragma unroll
        for (int im = 0; im < 2; ++im)
#pragma unroll
            for (int in_ = 0; in_ < 2; ++in_)
                acc[im][in_] = __builtin_amdgcn_mfma_f32_16x16x32_bf16(
                    af[im], bfr[in_], acc[im][in_], 0, 0, 0);
    }

    // epilogue: +bias, cast bf16, store
#pragma unroll
    for (int im = 0; im < 2; ++im) {
#pragma unroll
        for (int in_ = 0; in_ < 2; ++in_) {
            const int n = n0 + in_ * 16 + lr;           // C col = lane&15
            const float bv_ = bias[n];
#pragma unroll
            for (int r = 0; r < 4; ++r) {
                const int m = m0 + im * 16 + (lane >> 4) * 4 + r;  // C row
                const short v = f2bf(acc[im][in_][r] + bv_);
                if (z == 0)      Qb[(size_t)m * HID + n] = v;
                else if (z == 1) Kb[(size_t)m * HID + n] = v;
                else             Vt[(size_t)n * SEQ + m] = v;  // n = h*64+d
            }
        }
    }
}

// ---------------------------------------------------------------------------
// Kernel 2: flash attention. Grid (SEQ/64, NHEAD), 256 thr = 4 waves.
// Each wave: 16 q-rows, full D=64 output; loop K in tiles of 64.
// Online softmax in log2 domain; P staged via per-wave swizzled LDS.
// ---------------------------------------------------------------------------
__global__ __launch_bounds__(256) void attn_kernel(
    const short* __restrict__ Qb, const short* __restrict__ Kb,
    const short* __restrict__ Vt, const float* __restrict__ mask,
    float* __restrict__ out)
{
    const int h    = blockIdx.y;
    const int lane = threadIdx.x & 63;
    const int w    = threadIdx.x >> 6;
    const int q0   = blockIdx.x * 64 + w * 16;
    const int lr   = lane & 15;
    const int lk8  = (lane >> 4) * 8;
    const int crow = (lane >> 4) * 4;   // C-layout row base for this lane

    __shared__ __align__(16) short pbuf[4][16 * 64];  // per-wave P tile, swizzled

    // Q fragments (kept in registers for whole K loop)
    const short* qp = Qb + (size_t)(q0 + lr) * HID + h * HDIM + lk8;
    const bf16x8 qa0 = *reinterpret_cast<const bf16x8*>(qp);
    const bf16x8 qa1 = *reinterpret_cast<const bf16x8*>(qp + 32);

    f32x4 o[4] = {};
    float m_r[4] = {-INFINITY, -INFINITY, -INFINITY, -INFINITY};
    float l_r[4] = {0.f, 0.f, 0.f, 0.f};

    const float SC = 0.125f * 1.44269504088896340736f;  // (1/sqrt(64))*log2(e)
    const float ML = 1.44269504088896340736f;

    for (int kt = 0; kt < SEQ; kt += 64) {
        // ---- QK^T: S[16q][64k]
        f32x4 sacc[4];
#pragma unroll
        for (int g = 0; g < 4; ++g) {
            const short* kp = Kb + (size_t)(kt + g * 16 + lr) * HID + h * HDIM + lk8;
            bf16x8 kf0 = *reinterpret_cast<const bf16x8*>(kp);
            bf16x8 kf1 = *reinterpret_cast<const bf16x8*>(kp + 32);
            f32x4 zz = {};
            zz = __builtin_amdgcn_mfma_f32_16x16x32_bf16(qa0, kf0, zz, 0, 0, 0);
            zz = __builtin_amdgcn_mfma_f32_16x16x32_bf16(qa1, kf1, zz, 0, 0, 0);
            sacc[g] = zz;
        }

        // ---- scale + mask in log2 domain
        float s2[4][4];
#pragma unroll
        for (int g = 0; g < 4; ++g) {
            const float mk = mask[kt + g * 16 + lr] * ML;
#pragma unroll
            for (int r = 0; r < 4; ++r) s2[g][r] = fmaf(sacc[g][r], SC, mk);
        }

        // ---- online softmax: row max, rescale factors
        float sc_[4];
#pragma unroll
        for (int r = 0; r < 4; ++r) {
            float t = fmaxf(fmaxf(s2[0][r], s2[1][r]), fmaxf(s2[2][r], s2[3][r]));
            t = fmaxf(t, __shfl_xor(t, 1));
            t = fmaxf(t, __shfl_xor(t, 2));
            t = fmaxf(t, __shfl_xor(t, 4));
            t = fmaxf(t, __shfl_xor(t, 8));
            const float newm = fmaxf(m_r[r], t);
            sc_[r] = exp2f(m_r[r] - newm);
            m_r[r] = newm;
        }

        // ---- P = exp2(s2 - m), partial l, store P to swizzled LDS
#pragma unroll
        for (int r = 0; r < 4; ++r) {
            const int row = crow + r;
            const int swz = (row & 7) << 4;
            float ps = 0.f;
#pragma unroll
            for (int g = 0; g < 4; ++g) {
                const float p = exp2f(s2[g][r] - m_r[r]);
                ps += p;
                const int colb = (g * 16 + lr) * 2;
                pbuf[w][(row * 128 + (colb ^ swz)) >> 1] = f2bf(p);
            }
            l_r[r] = l_r[r] * sc_[r] + ps;
            o[0][r] *= sc_[r]; o[1][r] *= sc_[r];
            o[2][r] *= sc_[r]; o[3][r] *= sc_[r];
        }

        // ---- read P back as A fragments (16B swizzled reads)
        const int psw = (lr & 7) << 4;
        const bf16x8 pa0 = *reinterpret_cast<const bf16x8*>(
            &pbuf[w][(lr * 128 + ((lk8 * 2) ^ psw)) >> 1]);
        const bf16x8 pa1 = *reinterpret_cast<const bf16x8*>(
            &pbuf[w][(lr * 128 + ((64 + lk8 * 2) ^ psw)) >> 1]);

        // ---- PV: O[16q][64d] += P[16][64] * V[64][64]
#pragma unroll
        for (int c = 0; c < 4; ++c) {
            const short* vp = Vt + (size_t)(h * HDIM + c * 16 + lr) * SEQ + kt + lk8;
            bf16x8 vb0 = *reinterpret_cast<const bf16x8*>(vp);
            bf16x8 vb1 = *reinterpret_cast<const bf16x8*>(vp + 32);
            o[c] = __builtin_amdgcn_mfma_f32_16x16x32_bf16(pa0, vb0, o[c], 0, 0, 0);
            o[c] = __builtin_amdgcn_mfma_f32_16x16x32_bf16(pa1, vb1, o[c], 0, 0, 0);
        }
    }

    // ---- finalize: reduce l across the 16-lane group, divide, store fp32
#pragma unroll
    for (int r = 0; r < 4; ++r) {
        float t = l_r[r];
        t += __shfl_xor(t, 1);
        t += __shfl_xor(t, 2);
        t += __shfl_xor(t, 4);
        t += __shfl_xor(t, 8);
        l_r[r] = 1.0f / t;
    }
#pragma unroll
    for (int c = 0; c < 4; ++c) {
#pragma unroll
        for (int r = 0; r < 4; ++r) {
            const int row = q0 + crow + r;
            out[(size_t)row * HID + h * HDIM + c * 16 + lr] = o[c][r] * l_r[r];
        }
    }
}

// ---------------------------------------------------------------------------
extern "C" void kernel_launch(void* const* d_in, const int* in_sizes, int n_in,
                              void* d_out, int out_size, void* d_ws, size_t ws_size,
                              hipStream_t stream) {
    const float* hs   = (const float*)d_in[0];
    const float* mask = (const float*)d_in[1];
    const float* Wq   = (const float*)d_in[2];
    const float* bq   = (const float*)d_in[3];
    const float* Wk   = (const float*)d_in[4];
    const float* bk   = (const float*)d_in[5];
    const float* Wv   = (const float*)d_in[6];
    const float* bv   = (const float*)d_in[7];

    short* Qb = (short*)d_ws;                      // bf16 [SEQ][HID]
    short* Kb = Qb + (size_t)SEQ * HID;            // bf16 [SEQ][HID]
    short* Vt = Kb + (size_t)SEQ * HID;            // bf16 [HID][SEQ]
    float* out = (float*)d_out;

    dim3 g1(HID / 64, SEQ / 64, 3);
    qkv_proj_kernel<<<g1, 256, 0, stream>>>(hs, Wq, bq, Wk, bk, Wv, bv, Qb, Kb, Vt);

    dim3 g2(SEQ / 64, NHEAD);
    attn_kernel<<<g2, 256, 0, stream>>>(Qb, Kb, Vt, mask, out);
}

// Round 2
// 220.387 us; speedup vs baseline: 2.4722x; 2.4722x over previous
//
#include <hip/hip_runtime.h>
#include <hip/hip_bf16.h>

#define SEQ 4096
#define HID 768
#define NHEAD 12
#define HDIM 64
#define KVB 64
#define NT (SEQ / KVB)

typedef __attribute__((ext_vector_type(8))) short bf16x8;
typedef __attribute__((ext_vector_type(4))) float f32x4;
typedef __attribute__((ext_vector_type(4))) short s16x4;

static __device__ __forceinline__ short f2bf(float f) {
    unsigned u = __builtin_bit_cast(unsigned, f);
    unsigned r = (u + 0x7fffu + ((u >> 16) & 1u)) >> 16;
    return (short)r;
}
static __device__ __forceinline__ float bf2f(unsigned short u) {
    return __builtin_bit_cast(float, (unsigned)u << 16);
}
static __device__ __forceinline__ unsigned cvtpk(float lo, float hi) {
    unsigned r;
    asm("v_cvt_pk_bf16_f32 %0, %1, %2" : "=v"(r) : "v"(lo), "v"(hi));
    return r;
}
static __device__ __forceinline__ void glds16(const void* g, void* l) {
    __builtin_amdgcn_global_load_lds(
        (const __attribute__((address_space(1))) unsigned*)g,
        (__attribute__((address_space(3))) unsigned*)l, 16, 0, 0);
}

// ---------------------------------------------------------------------------
// fp32 -> bf16 cast, 8 elems/thread, grid sized exactly.
// ---------------------------------------------------------------------------
__global__ __launch_bounds__(256) void cast_bf16_kernel(
    const float* __restrict__ src, short* __restrict__ dst)
{
    const size_t i = (size_t)blockIdx.x * 256 + threadIdx.x;
    const float4* s = reinterpret_cast<const float4*>(src) + i * 2;
    const float4 a = s[0], b = s[1];
    bf16x8 o;
    o[0] = f2bf(a.x); o[1] = f2bf(a.y); o[2] = f2bf(a.z); o[3] = f2bf(a.w);
    o[4] = f2bf(b.x); o[5] = f2bf(b.y); o[6] = f2bf(b.z); o[7] = f2bf(b.w);
    reinterpret_cast<bf16x8*>(dst)[i] = o;
}

__global__ __launch_bounds__(256) void cast_w_kernel(
    const float* __restrict__ Wq, const float* __restrict__ Wk,
    const float* __restrict__ Wv, short* __restrict__ dst)
{
    const int z = blockIdx.y;
    const float* src = (z == 0) ? Wq : ((z == 1) ? Wk : Wv);
    const size_t i = (size_t)blockIdx.x * 256 + threadIdx.x;
    const float4* s = reinterpret_cast<const float4*>(src) + i * 2;
    const float4 a = s[0], b = s[1];
    bf16x8 o;
    o[0] = f2bf(a.x); o[1] = f2bf(a.y); o[2] = f2bf(a.z); o[3] = f2bf(a.w);
    o[4] = f2bf(b.x); o[5] = f2bf(b.y); o[6] = f2bf(b.z); o[7] = f2bf(b.w);
    reinterpret_cast<bf16x8*>(dst + (size_t)z * HID * HID)[i] = o;
}

// ---------------------------------------------------------------------------
// QKV projection from bf16 inputs. Block tile 128(m) x 256(n), 8 waves (2x4),
// each wave a 64x64 quadrant (4x4 MFMA 16x16x32, bf16).
// z<2 (Q,K): compute C[n][m] (A=W rows) so stores to [m][n] are short4-contig.
// z==2 (V): compute C[m][n] (A=hs rows) so stores to Vt[n][m] are short4-contig.
// ---------------------------------------------------------------------------
__global__ __launch_bounds__(512) void qkv_proj_kernel(
    const short* __restrict__ hsb, const short* __restrict__ Wb,
    const float* __restrict__ bq, const float* __restrict__ bk,
    const float* __restrict__ bv,
    short* __restrict__ Qb, short* __restrict__ Kb, short* __restrict__ Vt)
{
    const int z = blockIdx.z;
    const short* W = Wb + (size_t)z * HID * HID;
    const float* bias = (z == 0) ? bq : ((z == 1) ? bk : bv);

    const int lane = threadIdx.x & 63;
    const int w    = threadIdx.x >> 6;
    const int lr = lane & 15, hi = lane >> 4;
    const int wm = w >> 2, wn = w & 3;       // 2 x 4 wave grid
    const int m0 = blockIdx.y * 128 + wm * 64;
    const int n0 = blockIdx.x * 256 + wn * 64;

    const short* Aptr; const short* Bptr; int arow0, brow0;
    if (z < 2) { Aptr = W;   arow0 = n0; Bptr = hsb; brow0 = m0; }
    else       { Aptr = hsb; arow0 = m0; Bptr = W;   brow0 = n0; }

    f32x4 acc[4][4] = {};

    for (int k0 = 0; k0 < HID; k0 += 32) {
        bf16x8 af[4], bv_[4];
#pragma unroll
        for (int i = 0; i < 4; ++i)
            af[i] = *reinterpret_cast<const bf16x8*>(
                Aptr + (size_t)(arow0 + i * 16 + lr) * HID + k0 + hi * 8);
#pragma unroll
        for (int i = 0; i < 4; ++i)
            bv_[i] = *reinterpret_cast<const bf16x8*>(
                Bptr + (size_t)(brow0 + i * 16 + lr) * HID + k0 + hi * 8);
#pragma unroll
        for (int ia = 0; ia < 4; ++ia)
#pragma unroll
            for (int ib = 0; ib < 4; ++ib)
                acc[ia][ib] = __builtin_amdgcn_mfma_f32_16x16x32_bf16(
                    af[ia], bv_[ib], acc[ia][ib], 0, 0, 0);
    }

    if (z < 2) {
        short* outp = (z == 0) ? Qb : Kb;
#pragma unroll
        for (int ia = 0; ia < 4; ++ia) {
            const int nb = arow0 + ia * 16 + hi * 4;       // n (C-row base)
            const float4 b4 = *reinterpret_cast<const float4*>(bias + nb);
#pragma unroll
            for (int ib = 0; ib < 4; ++ib) {
                const int m = brow0 + ib * 16 + lr;        // m (C-col)
                s16x4 v;
                v[0] = f2bf(acc[ia][ib][0] + b4.x);
                v[1] = f2bf(acc[ia][ib][1] + b4.y);
                v[2] = f2bf(acc[ia][ib][2] + b4.z);
                v[3] = f2bf(acc[ia][ib][3] + b4.w);
                *reinterpret_cast<s16x4*>(outp + (size_t)m * HID + nb) = v;
            }
        }
    } else {
#pragma unroll
        for (int ib = 0; ib < 4; ++ib) {
            const int n = brow0 + ib * 16 + lr;            // n (C-col)
            const float bb = bias[n];
#pragma unroll
            for (int ia = 0; ia < 4; ++ia) {
                const int mb = arow0 + ia * 16 + hi * 4;   // m (C-row base)
                s16x4 v;
                v[0] = f2bf(acc[ia][ib][0] + bb);
                v[1] = f2bf(acc[ia][ib][1] + bb);
                v[2] = f2bf(acc[ia][ib][2] + bb);
                v[3] = f2bf(acc[ia][ib][3] + bb);
                *reinterpret_cast<s16x4*>(Vt + (size_t)n * SEQ + mb) = v;
            }
        }
    }
}

// ---------------------------------------------------------------------------
// Flash attention, swapped-QK^T layout. Grid (SEQ/64, NHEAD), 4 waves.
// LDS: K dbuf 2x8KB @0, V dbuf 2x8KB @16384, mask bf16 8KB @32768,
//      per-wave P buf 4x2KB @40960. Total 48KB -> 3 blocks/CU.
// K/V staged via global_load_lds with source-side XOR swizzle (row&7 on 16B
// units); reads apply the same swizzle -> conflict-free ds_read_b128.
// ---------------------------------------------------------------------------
static __device__ __forceinline__ void stage_kv(
    char* lds, int buf, int kt, int h, int w, int lane,
    const short* __restrict__ Kb, const short* __restrict__ Vt)
{
#pragma unroll
    for (int j = 0; j < 2; ++j) {
        const int R0  = (w * 2 + j) * 8;
        const int row = R0 + (lane >> 3);
        const int c16 = (lane & 7) ^ ((lane >> 3) & 7);
        const short* gk = Kb + (size_t)(kt + row) * HID + h * HDIM + c16 * 8;
        glds16(gk, lds + buf * 8192 + (w * 2 + j) * 1024);
        const short* gv = Vt + (size_t)(h * HDIM + row) * SEQ + kt + c16 * 8;
        glds16(gv, lds + 16384 + buf * 8192 + (w * 2 + j) * 1024);
    }
}

__global__ __launch_bounds__(256, 3) void attn_kernel(
    const short* __restrict__ Qb, const short* __restrict__ Kb,
    const short* __restrict__ Vt, const float* __restrict__ maskp,
    float* __restrict__ out)
{
    __shared__ __align__(16) char lds[49152];
    const int tid  = threadIdx.x;
    const int lane = tid & 63;
    const int w    = tid >> 6;
    const int lr = lane & 15, hi = lane >> 4;
    const int h  = blockIdx.y;
    const int q0 = blockIdx.x * 64 + w * 16;

    const float ML = 1.44269504088896340736f;
    const float SC = 0.125f * ML;

    // stage mask (pre-scaled by log2e) as bf16
    {
        short* mb = (short*)(lds + 32768);
        const int base = tid * 16;
#pragma unroll
        for (int i = 0; i < 4; ++i) {
            const float4 m4 = *reinterpret_cast<const float4*>(maskp + base + i * 4);
            s16x4 v;
            v[0] = f2bf(m4.x * ML); v[1] = f2bf(m4.y * ML);
            v[2] = f2bf(m4.z * ML); v[3] = f2bf(m4.w * ML);
            *reinterpret_cast<s16x4*>(mb + base + i * 4) = v;
        }
    }

    // Q fragments (held in registers for the whole loop)
    const short* qp = Qb + (size_t)(q0 + lr) * HID + h * HDIM + hi * 8;
    const bf16x8 qa0 = *reinterpret_cast<const bf16x8*>(qp);
    const bf16x8 qa1 = *reinterpret_cast<const bf16x8*>(qp + 32);

    stage_kv(lds, 0, 0, h, w, lane, Kb, Vt);
    __syncthreads();

    f32x4 oAcc[4] = {};
    float m_r = -INFINITY, ls = 0.f;
    const int sw = lr & 7;

    for (int t = 0; t < NT; ++t) {
        const int kt  = t * KVB;
        const int buf = t & 1;
        if (t + 1 < NT) stage_kv(lds, buf ^ 1, kt + KVB, h, w, lane, Kb, Vt);

        // ---- QK^T (swapped): C[key][q], lane holds 16 key-scores for q=lr
        const char* KT = lds + buf * 8192;
        float s2[4][4];
        float tmax = -INFINITY;
#pragma unroll
        for (int g = 0; g < 4; ++g) {
            const int rb = (g * 16 + lr) * 128;
            const bf16x8 kf0 = *reinterpret_cast<const bf16x8*>(KT + rb + ((hi ^ sw) << 4));
            const bf16x8 kf1 = *reinterpret_cast<const bf16x8*>(KT + rb + (((4 + hi) ^ sw) << 4));
            f32x4 zz = {};
            zz = __builtin_amdgcn_mfma_f32_16x16x32_bf16(kf0, qa0, zz, 0, 0, 0);
            zz = __builtin_amdgcn_mfma_f32_16x16x32_bf16(kf1, qa1, zz, 0, 0, 0);
            const s16x4 mkv = *reinterpret_cast<const s16x4*>(
                (const short*)(lds + 32768) + kt + g * 16 + hi * 4);
#pragma unroll
            for (int r = 0; r < 4; ++r) {
                s2[g][r] = fmaf(zz[r], SC, bf2f((unsigned short)mkv[r]));
                tmax = fmaxf(tmax, s2[g][r]);
            }
        }
        tmax = fmaxf(tmax, __shfl_xor(tmax, 16));
        tmax = fmaxf(tmax, __shfl_xor(tmax, 32));

        // ---- defer-max online rescale (THR=8)
        if (__ballot(tmax > m_r + 8.f)) {
            const float newm = fmaxf(m_r, tmax);
            const float sc = exp2f(fmaxf(m_r - newm, -128.f));
            ls *= sc;
#pragma unroll
            for (int c = 0; c < 4; ++c) oAcc[c] *= sc;
            m_r = newm;
        }

        // ---- P = exp2(s2-m), pack bf16 pairs, stage via per-wave swizzled LDS
        unsigned pk0[4], pk1[4];
#pragma unroll
        for (int g = 0; g < 4; ++g) {
            const float p0 = exp2f(s2[g][0] - m_r);
            const float p1 = exp2f(s2[g][1] - m_r);
            const float p2 = exp2f(s2[g][2] - m_r);
            const float p3 = exp2f(s2[g][3] - m_r);
            ls += (p0 + p1) + (p2 + p3);
            pk0[g] = cvtpk(p0, p1);
            pk1[g] = cvtpk(p2, p3);
        }
        char* pb = lds + 40960 + w * 2048;
#pragma unroll
        for (int g = 0; g < 4; ++g) {
            uint2 u; u.x = pk0[g]; u.y = pk1[g];
            *reinterpret_cast<uint2*>(pb + lr * 128 + ((g * 32 + hi * 8) ^ (sw << 4))) = u;
        }
        const bf16x8 pf0 = *reinterpret_cast<const bf16x8*>(
            pb + lr * 128 + ((hi * 16) ^ (sw << 4)));
        const bf16x8 pf1 = *reinterpret_cast<const bf16x8*>(
            pb + lr * 128 + ((64 + hi * 16) ^ (sw << 4)));

        // ---- PV: O^T[d][q] += V^T · P^T
        const char* VT = lds + 16384 + buf * 8192;
#pragma unroll
        for (int dg = 0; dg < 4; ++dg) {
            const int rb = (dg * 16 + lr) * 128;
            const bf16x8 v0 = *reinterpret_cast<const bf16x8*>(VT + rb + ((hi ^ sw) << 4));
            const bf16x8 v1 = *reinterpret_cast<const bf16x8*>(VT + rb + (((4 + hi) ^ sw) << 4));
            oAcc[dg] = __builtin_amdgcn_mfma_f32_16x16x32_bf16(v0, pf0, oAcc[dg], 0, 0, 0);
            oAcc[dg] = __builtin_amdgcn_mfma_f32_16x16x32_bf16(v1, pf1, oAcc[dg], 0, 0, 0);
        }
        __syncthreads();
    }

    // ---- finalize: l over hi-groups, divide, store fp32 (float4)
    float lt = ls;
    lt += __shfl_xor(lt, 16);
    lt += __shfl_xor(lt, 32);
    const float rl = 1.0f / lt;
    float* ob = out + (size_t)(q0 + lr) * HID + h * HDIM + hi * 4;
#pragma unroll
    for (int dg = 0; dg < 4; ++dg)
        *reinterpret_cast<f32x4*>(ob + dg * 16) = oAcc[dg] * rl;
}

// ---------------------------------------------------------------------------
extern "C" void kernel_launch(void* const* d_in, const int* in_sizes, int n_in,
                              void* d_out, int out_size, void* d_ws, size_t ws_size,
                              hipStream_t stream) {
    const float* hs   = (const float*)d_in[0];
    const float* mask = (const float*)d_in[1];
    const float* Wq   = (const float*)d_in[2];
    const float* bq   = (const float*)d_in[3];
    const float* Wk   = (const float*)d_in[4];
    const float* bk   = (const float*)d_in[5];
    const float* Wv   = (const float*)d_in[6];
    const float* bv   = (const float*)d_in[7];

    short* Qb = (short*)d_ws;                       // bf16 [SEQ][HID]
    short* Kb = Qb + (size_t)SEQ * HID;             // bf16 [SEQ][HID]
    short* Vt = Kb + (size_t)SEQ * HID;             // bf16 [HID][SEQ]
    float* out = (float*)d_out;

    // bf16 scratch carved from d_out (attn overwrites it at the very end):
    // hsb: 6.29MB, Wb: 3.54MB -> 9.83MB < 12.58MB out buffer.
    short* hsb = (short*)d_out;
    short* Wb  = hsb + (size_t)SEQ * HID;

    cast_bf16_kernel<<<dim3(SEQ * HID / 2048), 256, 0, stream>>>(hs, hsb);
    cast_w_kernel<<<dim3(HID * HID / 2048, 3), 256, 0, stream>>>(Wq, Wk, Wv, Wb);

    qkv_proj_kernel<<<dim3(HID / 256, SEQ / 128, 3), 512, 0, stream>>>(
        hsb, Wb, bq, bk, bv, Qb, Kb, Vt);

    attn_kernel<<<dim3(SEQ / 64, NHEAD), 256, 0, stream>>>(Qb, Kb, Vt, mask, out);
}

// Round 3
// 194.218 us; speedup vs baseline: 2.8053x; 1.1347x over previous
//
#include <hip/hip_runtime.h>
#include <hip/hip_bf16.h>

#define SEQ 4096
#define HID 768
#define NHEAD 12
#define HDIM 64
#define KVB 64
#define NT (SEQ / KVB)   // 64
#define PBK 64
#define PNT (HID / PBK)  // 12

typedef __attribute__((ext_vector_type(8))) short bf16x8;
typedef __attribute__((ext_vector_type(4))) float f32x4;
typedef __attribute__((ext_vector_type(4))) short s16x4;

static __device__ __forceinline__ short f2bf(float f) {
    unsigned u = __builtin_bit_cast(unsigned, f);
    unsigned r = (u + 0x7fffu + ((u >> 16) & 1u)) >> 16;
    return (short)r;
}
static __device__ __forceinline__ float bf2f(unsigned short u) {
    return __builtin_bit_cast(float, (unsigned)u << 16);
}
static __device__ __forceinline__ unsigned cvtpk(float lo, float hi) {
    unsigned r;
    asm("v_cvt_pk_bf16_f32 %0, %1, %2" : "=v"(r) : "v"(lo), "v"(hi));
    return r;
}
static __device__ __forceinline__ float max3f(float a, float b, float c) {
    float r;
    asm("v_max3_f32 %0, %1, %2, %3" : "=v"(r) : "v"(a), "v"(b), "v"(c));
    return r;
}
static __device__ __forceinline__ void glds16(const void* g, void* l) {
    __builtin_amdgcn_global_load_lds(
        (const __attribute__((address_space(1))) unsigned*)g,
        (__attribute__((address_space(3))) unsigned*)l, 16, 0, 0);
}

// ---------------------------------------------------------------------------
// fp32 -> bf16 casts
// ---------------------------------------------------------------------------
__global__ __launch_bounds__(256) void cast_bf16_kernel(
    const float* __restrict__ src, short* __restrict__ dst)
{
    const size_t i = (size_t)blockIdx.x * 256 + threadIdx.x;
    const float4* s = reinterpret_cast<const float4*>(src) + i * 2;
    const float4 a = s[0], b = s[1];
    bf16x8 o;
    o[0] = f2bf(a.x); o[1] = f2bf(a.y); o[2] = f2bf(a.z); o[3] = f2bf(a.w);
    o[4] = f2bf(b.x); o[5] = f2bf(b.y); o[6] = f2bf(b.z); o[7] = f2bf(b.w);
    reinterpret_cast<bf16x8*>(dst)[i] = o;
}

__global__ __launch_bounds__(256) void cast_w_kernel(
    const float* __restrict__ Wq, const float* __restrict__ Wk,
    const float* __restrict__ Wv, short* __restrict__ dst)
{
    const int z = blockIdx.y;
    const float* src = (z == 0) ? Wq : ((z == 1) ? Wk : Wv);
    const size_t i = (size_t)blockIdx.x * 256 + threadIdx.x;
    const float4* s = reinterpret_cast<const float4*>(src) + i * 2;
    const float4 a = s[0], b = s[1];
    bf16x8 o;
    o[0] = f2bf(a.x); o[1] = f2bf(a.y); o[2] = f2bf(a.z); o[3] = f2bf(a.w);
    o[4] = f2bf(b.x); o[5] = f2bf(b.y); o[6] = f2bf(b.z); o[7] = f2bf(b.w);
    reinterpret_cast<bf16x8*>(dst + (size_t)z * HID * HID)[i] = o;
}

// ---------------------------------------------------------------------------
// QKV projection, LDS-staged (m97-style). Tile 128(m) x 128(n), BK=64,
// dbuf 64KB, raw-barrier + vmcnt(0) per K-step. 4 waves (2x2), each 64x64.
// Q output is pre-scaled by 0.125*log2e (folded softmax scale).
// ---------------------------------------------------------------------------
__global__ __launch_bounds__(256) void qkv_proj_kernel(
    const short* __restrict__ hsb, const short* __restrict__ Wb,
    const float* __restrict__ bq, const float* __restrict__ bk,
    const float* __restrict__ bv,
    short* __restrict__ Qb, short* __restrict__ Kb, short* __restrict__ Vt)
{
    __shared__ __align__(16) char lds[65536];  // A: 0/16384, B: 32768/49152
    const int z = blockIdx.z;
    const float* bias = (z == 0) ? bq : ((z == 1) ? bk : bv);

    const int lane = threadIdx.x & 63;
    const int w    = threadIdx.x >> 6;
    const int lr = lane & 15, hi = lane >> 4;
    const int wi = w >> 1, wj = w & 1;

    const short* Ag; const short* Bg; int ar0, br0;
    if (z < 2) { Ag = Wb + (size_t)z * HID * HID; ar0 = blockIdx.x * 128;
                 Bg = hsb;                        br0 = blockIdx.y * 128; }
    else       { Ag = hsb;                        ar0 = blockIdx.y * 128;
                 Bg = Wb + (size_t)2 * HID * HID; br0 = blockIdx.x * 128; }

    const int rsub = lane >> 3;               // row within chunk (= row&7)
    const int c16  = (lane & 7) ^ rsub;       // swizzled 16B slot

    // stage one K-tile (A and B, 16KB each) into buffer `buf`
    auto stage = [&](int t, int buf) {
        const int k0 = t * PBK;
#pragma unroll
        for (int c = 0; c < 4; ++c) {
            const int ch = w * 4 + c;
            const int row = ch * 8 + rsub;
            glds16(Ag + (size_t)(ar0 + row) * HID + k0 + c16 * 8,
                   lds + buf * 16384 + ch * 1024);
            glds16(Bg + (size_t)(br0 + row) * HID + k0 + c16 * 8,
                   lds + 32768 + buf * 16384 + ch * 1024);
        }
    };

    stage(0, 0);
    f32x4 acc[4][4] = {};

    for (int t = 0; t < PNT; ++t) {
        asm volatile("s_waitcnt vmcnt(0)" ::: "memory");
        __builtin_amdgcn_s_barrier();
        __builtin_amdgcn_sched_barrier(0);
        if (t + 1 < PNT) stage(t + 1, (t + 1) & 1);
        const char* LA = lds + (t & 1) * 16384;
        const char* LB = lds + 32768 + (t & 1) * 16384;
#pragma unroll
        for (int ks = 0; ks < 2; ++ks) {
            bf16x8 af[4], bf_[4];
#pragma unroll
            for (int i = 0; i < 4; ++i) {
                const int rowA = wi * 64 + i * 16 + lr;
                af[i] = *reinterpret_cast<const bf16x8*>(
                    LA + rowA * 128 + (((ks * 4 + hi) ^ (rowA & 7)) << 4));
                const int rowB = wj * 64 + i * 16 + lr;
                bf_[i] = *reinterpret_cast<const bf16x8*>(
                    LB + rowB * 128 + (((ks * 4 + hi) ^ (rowB & 7)) << 4));
            }
            __builtin_amdgcn_s_setprio(1);
#pragma unroll
            for (int ia = 0; ia < 4; ++ia)
#pragma unroll
                for (int ib = 0; ib < 4; ++ib)
                    acc[ia][ib] = __builtin_amdgcn_mfma_f32_16x16x32_bf16(
                        af[ia], bf_[ib], acc[ia][ib], 0, 0, 0);
            __builtin_amdgcn_s_setprio(0);
        }
    }

    const float SCQ = 0.125f * 1.44269504088896340736f;
    if (z < 2) {
        short* outp = (z == 0) ? Qb : Kb;
        const float sc = (z == 0) ? SCQ : 1.0f;
#pragma unroll
        for (int ia = 0; ia < 4; ++ia) {
            const int nb = ar0 + wi * 64 + ia * 16 + hi * 4;
            const float4 b4 = *reinterpret_cast<const float4*>(bias + nb);
#pragma unroll
            for (int ib = 0; ib < 4; ++ib) {
                const int m = br0 + wj * 64 + ib * 16 + lr;
                s16x4 v;
                v[0] = f2bf((acc[ia][ib][0] + b4.x) * sc);
                v[1] = f2bf((acc[ia][ib][1] + b4.y) * sc);
                v[2] = f2bf((acc[ia][ib][2] + b4.z) * sc);
                v[3] = f2bf((acc[ia][ib][3] + b4.w) * sc);
                *reinterpret_cast<s16x4*>(outp + (size_t)m * HID + nb) = v;
            }
        }
    } else {
#pragma unroll
        for (int ib = 0; ib < 4; ++ib) {
            const int n = br0 + wj * 64 + ib * 16 + lr;
            const float bb = bias[n];
#pragma unroll
            for (int ia = 0; ia < 4; ++ia) {
                const int mb = ar0 + wi * 64 + ia * 16 + hi * 4;
                s16x4 v;
                v[0] = f2bf(acc[ia][ib][0] + bb);
                v[1] = f2bf(acc[ia][ib][1] + bb);
                v[2] = f2bf(acc[ia][ib][2] + bb);
                v[3] = f2bf(acc[ia][ib][3] + bb);
                *reinterpret_cast<s16x4*>(Vt + (size_t)n * SEQ + mb) = v;
            }
        }
    }
}

// ---------------------------------------------------------------------------
// Flash attention, counted-vmcnt 4-deep pipeline.
// LDS: K ring 4x8KB @0, V ring 4x8KB @32768, maskML bf16 8KB @65536,
//      per-wave P buf 4x2KB @73728. Total 80KB -> 2 blocks/CU.
// One raw s_barrier per tile; s_waitcnt vmcnt(8) (counted, never 0 mid-loop).
// QK^T C-init = mask*log2e; Q pre-scaled by 0.125*log2e at projection.
// ---------------------------------------------------------------------------
__global__ __launch_bounds__(256) void attn_kernel(
    const short* __restrict__ Qb, const short* __restrict__ Kb,
    const short* __restrict__ Vt, const float* __restrict__ maskp,
    float* __restrict__ out)
{
    __shared__ __align__(16) char lds[81920];
    const int tid  = threadIdx.x;
    const int lane = tid & 63;
    const int w    = tid >> 6;
    const int lr = lane & 15, hi = lane >> 4;
    const int h  = blockIdx.y;
    const int q0 = blockIdx.x * 64 + w * 16;
    const int sw = lr & 7;
    const float ML = 1.44269504088896340736f;

    // stage mask*log2e as bf16 (once)
    {
        short* mb = (short*)(lds + 65536);
        const int base = tid * 16;
#pragma unroll
        for (int i = 0; i < 4; ++i) {
            const float4 m4 = *reinterpret_cast<const float4*>(maskp + base + i * 4);
            s16x4 v;
            v[0] = f2bf(m4.x * ML); v[1] = f2bf(m4.y * ML);
            v[2] = f2bf(m4.z * ML); v[3] = f2bf(m4.w * ML);
            *reinterpret_cast<s16x4*>(mb + base + i * 4) = v;
        }
    }

    // Q fragments (pre-scaled at projection)
    const short* qp = Qb + (size_t)(q0 + lr) * HID + h * HDIM + hi * 8;
    const bf16x8 qa0 = *reinterpret_cast<const bf16x8*>(qp);
    const bf16x8 qa1 = *reinterpret_cast<const bf16x8*>(qp + 32);

    __syncthreads();   // mask staged before pipeline starts

    const int srow = lane >> 3;
    const int sc16 = (lane & 7) ^ srow;
    auto stage = [&](int t, int buf) {
        const int kt = t * KVB;
#pragma unroll
        for (int j = 0; j < 2; ++j) {
            const int ch  = w * 2 + j;
            const int row = ch * 8 + srow;
            glds16(Kb + (size_t)(kt + row) * HID + h * HDIM + sc16 * 8,
                   lds + buf * 8192 + ch * 1024);
            glds16(Vt + (size_t)(h * HDIM + row) * SEQ + kt + sc16 * 8,
                   lds + 32768 + buf * 8192 + ch * 1024);
        }
    };

    stage(0, 0);
    stage(1, 1);

    f32x4 oAcc[4] = {};
    float m_r = -INFINITY, ls = 0.f;
    char* pb = lds + 73728 + w * 2048;
    const short* mlds = (const short*)(lds + 65536);

    for (int t = 0; t < NT; ++t) {
        const int kt = t * KVB;
        if (t + 2 < NT) {
            stage(t + 2, (t + 2) & 3);
            asm volatile("s_waitcnt vmcnt(8)" ::: "memory");
        } else if (t + 1 < NT) {
            asm volatile("s_waitcnt vmcnt(4)" ::: "memory");
        } else {
            asm volatile("s_waitcnt vmcnt(0)" ::: "memory");
        }
        __builtin_amdgcn_s_barrier();
        __builtin_amdgcn_sched_barrier(0);

        // ---- QK^T (swapped): C[key][q], C-init = mask*log2e
        const char* KT = lds + (t & 3) * 8192;
        float s2[4][4];
#pragma unroll
        for (int g = 0; g < 4; ++g) {
            const s16x4 mkv = *reinterpret_cast<const s16x4*>(
                mlds + kt + g * 16 + hi * 4);
            f32x4 zz;
            zz[0] = bf2f((unsigned short)mkv[0]);
            zz[1] = bf2f((unsigned short)mkv[1]);
            zz[2] = bf2f((unsigned short)mkv[2]);
            zz[3] = bf2f((unsigned short)mkv[3]);
            const int rb = (g * 16 + lr) * 128;
            const bf16x8 kf0 = *reinterpret_cast<const bf16x8*>(KT + rb + ((hi ^ sw) << 4));
            const bf16x8 kf1 = *reinterpret_cast<const bf16x8*>(KT + rb + (((4 + hi) ^ sw) << 4));
            __builtin_amdgcn_s_setprio(1);
            zz = __builtin_amdgcn_mfma_f32_16x16x32_bf16(kf0, qa0, zz, 0, 0, 0);
            zz = __builtin_amdgcn_mfma_f32_16x16x32_bf16(kf1, qa1, zz, 0, 0, 0);
            __builtin_amdgcn_s_setprio(0);
            s2[g][0] = zz[0]; s2[g][1] = zz[1]; s2[g][2] = zz[2]; s2[g][3] = zz[3];
        }

        // ---- row max via max3 tree + cross-group reduce
        float tmax;
        {
            const float a = max3f(s2[0][0], s2[0][1], s2[0][2]);
            const float b = max3f(s2[0][3], s2[1][0], s2[1][1]);
            const float c = max3f(s2[1][2], s2[1][3], s2[2][0]);
            const float d = max3f(s2[2][1], s2[2][2], s2[2][3]);
            const float e = max3f(s2[3][0], s2[3][1], s2[3][2]);
            tmax = max3f(max3f(a, b, c), max3f(d, e, s2[3][3]),
                         __builtin_bit_cast(float, 0xff800000u));
        }
        tmax = fmaxf(tmax, __shfl_xor(tmax, 16));
        tmax = fmaxf(tmax, __shfl_xor(tmax, 32));

        // ---- defer-max rescale (THR=8)
        if (__ballot(tmax > m_r + 8.f)) {
            const float newm = fmaxf(m_r, tmax);
            const float sc = exp2f(fmaxf(m_r - newm, -128.f));
            ls *= sc;
#pragma unroll
            for (int c = 0; c < 4; ++c) oAcc[c] *= sc;
            m_r = newm;
        }

        // ---- P = exp2(s2 - m), pack, stage via per-wave swizzled LDS
        unsigned pk0[4], pk1[4];
#pragma unroll
        for (int g = 0; g < 4; ++g) {
            const float p0 = exp2f(s2[g][0] - m_r);
            const float p1 = exp2f(s2[g][1] - m_r);
            const float p2 = exp2f(s2[g][2] - m_r);
            const float p3 = exp2f(s2[g][3] - m_r);
            ls += (p0 + p1) + (p2 + p3);
            pk0[g] = cvtpk(p0, p1);
            pk1[g] = cvtpk(p2, p3);
        }
#pragma unroll
        for (int g = 0; g < 4; ++g) {
            uint2 u; u.x = pk0[g]; u.y = pk1[g];
            *reinterpret_cast<uint2*>(pb + lr * 128 + ((g * 32 + hi * 8) ^ (sw << 4))) = u;
        }
        const bf16x8 pf0 = *reinterpret_cast<const bf16x8*>(
            pb + lr * 128 + ((hi * 16) ^ (sw << 4)));
        const bf16x8 pf1 = *reinterpret_cast<const bf16x8*>(
            pb + lr * 128 + ((64 + hi * 16) ^ (sw << 4)));

        // ---- PV: O^T[d][q] += V^T . P^T
        const char* VT = lds + 32768 + (t & 3) * 8192;
#pragma unroll
        for (int dg = 0; dg < 4; ++dg) {
            const int rb = (dg * 16 + lr) * 128;
            const bf16x8 v0 = *reinterpret_cast<const bf16x8*>(VT + rb + ((hi ^ sw) << 4));
            const bf16x8 v1 = *reinterpret_cast<const bf16x8*>(VT + rb + (((4 + hi) ^ sw) << 4));
            __builtin_amdgcn_s_setprio(1);
            oAcc[dg] = __builtin_amdgcn_mfma_f32_16x16x32_bf16(v0, pf0, oAcc[dg], 0, 0, 0);
            oAcc[dg] = __builtin_amdgcn_mfma_f32_16x16x32_bf16(v1, pf1, oAcc[dg], 0, 0, 0);
            __builtin_amdgcn_s_setprio(0);
        }
    }

    // ---- finalize
    float lt = ls;
    lt += __shfl_xor(lt, 16);
    lt += __shfl_xor(lt, 32);
    const float rl = 1.0f / lt;
    float* ob = out + (size_t)(q0 + lr) * HID + h * HDIM + hi * 4;
#pragma unroll
    for (int dg = 0; dg < 4; ++dg)
        *reinterpret_cast<f32x4*>(ob + dg * 16) = oAcc[dg] * rl;
}

// ---------------------------------------------------------------------------
extern "C" void kernel_launch(void* const* d_in, const int* in_sizes, int n_in,
                              void* d_out, int out_size, void* d_ws, size_t ws_size,
                              hipStream_t stream) {
    const float* hs   = (const float*)d_in[0];
    const float* mask = (const float*)d_in[1];
    const float* Wq   = (const float*)d_in[2];
    const float* bq   = (const float*)d_in[3];
    const float* Wk   = (const float*)d_in[4];
    const float* bk   = (const float*)d_in[5];
    const float* Wv   = (const float*)d_in[6];
    const float* bv   = (const float*)d_in[7];

    short* Qb = (short*)d_ws;                       // bf16 [SEQ][HID], pre-scaled
    short* Kb = Qb + (size_t)SEQ * HID;             // bf16 [SEQ][HID]
    short* Vt = Kb + (size_t)SEQ * HID;             // bf16 [HID][SEQ]
    float* out = (float*)d_out;

    // bf16 scratch carved from d_out (attn overwrites it at the very end)
    short* hsb = (short*)d_out;
    short* Wb  = hsb + (size_t)SEQ * HID;

    cast_bf16_kernel<<<dim3(SEQ * HID / 2048), 256, 0, stream>>>(hs, hsb);
    cast_w_kernel<<<dim3(HID * HID / 2048, 3), 256, 0, stream>>>(Wq, Wk, Wv, Wb);

    qkv_proj_kernel<<<dim3(HID / 128, SEQ / 128, 3), 256, 0, stream>>>(
        hsb, Wb, bq, bk, bv, Qb, Kb, Vt);

    attn_kernel<<<dim3(SEQ / KVB, NHEAD), 256, 0, stream>>>(Qb, Kb, Vt, mask, out);
}

// Round 4
// 151.856 us; speedup vs baseline: 3.5878x; 1.2790x over previous
//
#include <hip/hip_runtime.h>
#include <hip/hip_bf16.h>

#define SEQ 4096
#define HID 768
#define NHEAD 12
#define HDIM 64
#define KVB 64
#define NT (SEQ / KVB)   // 64
#define PBK 64
#define PNT (HID / PBK)  // 12

typedef __attribute__((ext_vector_type(8))) short bf16x8;
typedef __attribute__((ext_vector_type(4))) float f32x4;
typedef __attribute__((ext_vector_type(4))) short s16x4;

static __device__ __forceinline__ short f2bf(float f) {
    unsigned u = __builtin_bit_cast(unsigned, f);
    unsigned r = (u + 0x7fffu + ((u >> 16) & 1u)) >> 16;
    return (short)r;
}
static __device__ __forceinline__ float bf2f(unsigned short u) {
    return __builtin_bit_cast(float, (unsigned)u << 16);
}
static __device__ __forceinline__ unsigned cvtpk(float lo, float hi) {
    unsigned r;
    asm("v_cvt_pk_bf16_f32 %0, %1, %2" : "=v"(r) : "v"(lo), "v"(hi));
    return r;
}
static __device__ __forceinline__ float max3f(float a, float b, float c) {
    float r;
    asm("v_max3_f32 %0, %1, %2, %3" : "=v"(r) : "v"(a), "v"(b), "v"(c));
    return r;
}
static __device__ __forceinline__ void glds16(const void* g, void* l) {
    __builtin_amdgcn_global_load_lds(
        (const __attribute__((address_space(1))) unsigned*)g,
        (__attribute__((address_space(3))) unsigned*)l, 16, 0, 0);
}

// ---------------------------------------------------------------------------
// fp32 -> bf16 casts
// ---------------------------------------------------------------------------
__global__ __launch_bounds__(256) void cast_bf16_kernel(
    const float* __restrict__ src, short* __restrict__ dst)
{
    const size_t i = (size_t)blockIdx.x * 256 + threadIdx.x;
    const float4* s = reinterpret_cast<const float4*>(src) + i * 2;
    const float4 a = s[0], b = s[1];
    bf16x8 o;
    o[0] = f2bf(a.x); o[1] = f2bf(a.y); o[2] = f2bf(a.z); o[3] = f2bf(a.w);
    o[4] = f2bf(b.x); o[5] = f2bf(b.y); o[6] = f2bf(b.z); o[7] = f2bf(b.w);
    reinterpret_cast<bf16x8*>(dst)[i] = o;
}

__global__ __launch_bounds__(256) void cast_w_kernel(
    const float* __restrict__ Wq, const float* __restrict__ Wk,
    const float* __restrict__ Wv, short* __restrict__ dst)
{
    const int z = blockIdx.y;
    const float* src = (z == 0) ? Wq : ((z == 1) ? Wk : Wv);
    const size_t i = (size_t)blockIdx.x * 256 + threadIdx.x;
    const float4* s = reinterpret_cast<const float4*>(src) + i * 2;
    const float4 a = s[0], b = s[1];
    bf16x8 o;
    o[0] = f2bf(a.x); o[1] = f2bf(a.y); o[2] = f2bf(a.z); o[3] = f2bf(a.w);
    o[4] = f2bf(b.x); o[5] = f2bf(b.y); o[6] = f2bf(b.z); o[7] = f2bf(b.w);
    reinterpret_cast<bf16x8*>(dst + (size_t)z * HID * HID)[i] = o;
}

// ---------------------------------------------------------------------------
// QKV projection, LDS-staged. Tile 128x128, BK=64, dbuf 64KB.
// Q output pre-scaled by 0.125*log2e (folds the softmax scale).
// ---------------------------------------------------------------------------
__global__ __launch_bounds__(256) void qkv_proj_kernel(
    const short* __restrict__ hsb, const short* __restrict__ Wb,
    const float* __restrict__ bq, const float* __restrict__ bk,
    const float* __restrict__ bv,
    short* __restrict__ Qb, short* __restrict__ Kb, short* __restrict__ Vt)
{
    __shared__ __align__(16) char lds[65536];
    const int z = blockIdx.z;
    const float* bias = (z == 0) ? bq : ((z == 1) ? bk : bv);

    const int lane = threadIdx.x & 63;
    const int w    = threadIdx.x >> 6;
    const int lr = lane & 15, hi = lane >> 4;
    const int wi = w >> 1, wj = w & 1;

    const short* Ag; const short* Bg; int ar0, br0;
    if (z < 2) { Ag = Wb + (size_t)z * HID * HID; ar0 = blockIdx.x * 128;
                 Bg = hsb;                        br0 = blockIdx.y * 128; }
    else       { Ag = hsb;                        ar0 = blockIdx.y * 128;
                 Bg = Wb + (size_t)2 * HID * HID; br0 = blockIdx.x * 128; }

    const int rsub = lane >> 3;
    const int c16  = (lane & 7) ^ rsub;

    auto stage = [&](int t, int buf) {
        const int k0 = t * PBK;
#pragma unroll
        for (int c = 0; c < 4; ++c) {
            const int ch = w * 4 + c;
            const int row = ch * 8 + rsub;
            glds16(Ag + (size_t)(ar0 + row) * HID + k0 + c16 * 8,
                   lds + buf * 16384 + ch * 1024);
            glds16(Bg + (size_t)(br0 + row) * HID + k0 + c16 * 8,
                   lds + 32768 + buf * 16384 + ch * 1024);
        }
    };

    stage(0, 0);
    f32x4 acc[4][4] = {};

    for (int t = 0; t < PNT; ++t) {
        asm volatile("s_waitcnt vmcnt(0)" ::: "memory");
        __builtin_amdgcn_s_barrier();
        __builtin_amdgcn_sched_barrier(0);
        if (t + 1 < PNT) stage(t + 1, (t + 1) & 1);
        const char* LA = lds + (t & 1) * 16384;
        const char* LB = lds + 32768 + (t & 1) * 16384;
#pragma unroll
        for (int ks = 0; ks < 2; ++ks) {
            bf16x8 af[4], bf_[4];
#pragma unroll
            for (int i = 0; i < 4; ++i) {
                const int rowA = wi * 64 + i * 16 + lr;
                af[i] = *reinterpret_cast<const bf16x8*>(
                    LA + rowA * 128 + (((ks * 4 + hi) ^ (rowA & 7)) << 4));
                const int rowB = wj * 64 + i * 16 + lr;
                bf_[i] = *reinterpret_cast<const bf16x8*>(
                    LB + rowB * 128 + (((ks * 4 + hi) ^ (rowB & 7)) << 4));
            }
            __builtin_amdgcn_s_setprio(1);
#pragma unroll
            for (int ia = 0; ia < 4; ++ia)
#pragma unroll
                for (int ib = 0; ib < 4; ++ib)
                    acc[ia][ib] = __builtin_amdgcn_mfma_f32_16x16x32_bf16(
                        af[ia], bf_[ib], acc[ia][ib], 0, 0, 0);
            __builtin_amdgcn_s_setprio(0);
        }
    }

    const float SCQ = 0.125f * 1.44269504088896340736f;
    if (z < 2) {
        short* outp = (z == 0) ? Qb : Kb;
        const float sc = (z == 0) ? SCQ : 1.0f;
#pragma unroll
        for (int ia = 0; ia < 4; ++ia) {
            const int nb = ar0 + wi * 64 + ia * 16 + hi * 4;
            const float4 b4 = *reinterpret_cast<const float4*>(bias + nb);
#pragma unroll
            for (int ib = 0; ib < 4; ++ib) {
                const int m = br0 + wj * 64 + ib * 16 + lr;
                s16x4 v;
                v[0] = f2bf((acc[ia][ib][0] + b4.x) * sc);
                v[1] = f2bf((acc[ia][ib][1] + b4.y) * sc);
                v[2] = f2bf((acc[ia][ib][2] + b4.z) * sc);
                v[3] = f2bf((acc[ia][ib][3] + b4.w) * sc);
                *reinterpret_cast<s16x4*>(outp + (size_t)m * HID + nb) = v;
            }
        }
    } else {
#pragma unroll
        for (int ib = 0; ib < 4; ++ib) {
            const int n = br0 + wj * 64 + ib * 16 + lr;
            const float bb = bias[n];
#pragma unroll
            for (int ia = 0; ia < 4; ++ia) {
                const int mb = ar0 + wi * 64 + ia * 16 + hi * 4;
                s16x4 v;
                v[0] = f2bf(acc[ia][ib][0] + bb);
                v[1] = f2bf(acc[ia][ib][1] + bb);
                v[2] = f2bf(acc[ia][ib][2] + bb);
                v[3] = f2bf(acc[ia][ib][3] + bb);
                *reinterpret_cast<s16x4*>(Vt + (size_t)n * SEQ + mb) = v;
            }
        }
    }
}

// ---------------------------------------------------------------------------
// Flash attention, zero-shuffle P via key-permuted QK^T.
// MFMA g computes keys hi*8 + (g&1)*4 + r + (g>>1)*32, so each lane's 16
// scores ARE its PV B-fragment -> P = in-register cvt_pk, no LDS round-trip.
// LDS: K dbuf 2x8KB @0, V dbuf 2x8KB @16384, maskML bf16 8KB @32768. 40KB.
// Swizzle f(row) = (row&7) ^ ((row>>1)&4)  (2-way max for permuted K reads
// and natural V reads; applied on both the glds source and the ds_read).
// ---------------------------------------------------------------------------
__global__ __launch_bounds__(256, 4) void attn_kernel(
    const short* __restrict__ Qb, const short* __restrict__ Kb,
    const short* __restrict__ Vt, const float* __restrict__ maskp,
    float* __restrict__ out)
{
    __shared__ __align__(16) char lds[40960];
    const int tid  = threadIdx.x;
    const int lane = tid & 63;
    const int w    = tid >> 6;
    const int lr = lane & 15, hi = lane >> 4;
    const int h  = blockIdx.y;
    const int q0 = blockIdx.x * 64 + w * 16;
    const float ML = 1.44269504088896340736f;

    const int srow = lane >> 3;
    auto stage = [&](int t, int buf) {
        const int kt = t * KVB;
#pragma unroll
        for (int j = 0; j < 2; ++j) {
            const int ch  = w * 2 + j;
            const int row = ch * 8 + srow;
            const int c16 = (lane & 7) ^ srow ^ ((ch & 1) << 2);
            glds16(Kb + (size_t)(kt + row) * HID + h * HDIM + c16 * 8,
                   lds + buf * 8192 + ch * 1024);
            glds16(Vt + (size_t)(h * HDIM + row) * SEQ + kt + c16 * 8,
                   lds + 16384 + buf * 8192 + ch * 1024);
        }
    };

    stage(0, 0);   // in flight across the mask staging

    // stage mask*log2e as bf16 (once)
    {
        short* mb = (short*)(lds + 32768);
        const int base = tid * 16;
#pragma unroll
        for (int i = 0; i < 4; ++i) {
            const float4 m4 = *reinterpret_cast<const float4*>(maskp + base + i * 4);
            s16x4 v;
            v[0] = f2bf(m4.x * ML); v[1] = f2bf(m4.y * ML);
            v[2] = f2bf(m4.z * ML); v[3] = f2bf(m4.w * ML);
            *reinterpret_cast<s16x4*>(mb + base + i * 4) = v;
        }
    }

    // Q fragments (pre-scaled by 0.125*log2e at projection)
    const short* qp = Qb + (size_t)(q0 + lr) * HID + h * HDIM + hi * 8;
    const bf16x8 qa0 = *reinterpret_cast<const bf16x8*>(qp);
    const bf16x8 qa1 = *reinterpret_cast<const bf16x8*>(qp + 32);

    __syncthreads();   // mask visible to all waves (also drains stage(0))

    f32x4 oAcc[4] = {};
    float m_r = -INFINITY, ls = 0.f;
    const short* mlds = (const short*)(lds + 32768);

    // t-invariant LDS offsets
    const int kbase = ((lr >> 2) * 8) + (lr & 3);     // key-permutation base
    const int fv    = (lr & 7) ^ ((lr >> 1) & 4);     // V-row swizzle

    for (int t = 0; t < NT; ++t) {
        const int kt = t * KVB;
        asm volatile("s_waitcnt vmcnt(0)" ::: "memory");  // stage(t) landed
        __builtin_amdgcn_s_barrier();
        __builtin_amdgcn_sched_barrier(0);
        if (t + 1 < NT) stage(t + 1, (t + 1) & 1);  // buf read at t-1: safe

        // ---- QK^T, key-permuted: lane gets scores for keys
        //      hi*8 + (g&1)*4 + r + (g>>1)*32  (q = lr), C-init = mask*log2e
        const char* KT = lds + (t & 1) * 8192;
        float s2[4][4];
#pragma unroll
        for (int g = 0; g < 4; ++g) {
            const int mk0 = hi * 8 + (g & 1) * 4 + (g >> 1) * 32;
            const s16x4 mkv = *reinterpret_cast<const s16x4*>(mlds + kt + mk0);
            f32x4 zz;
            zz[0] = bf2f((unsigned short)mkv[0]);
            zz[1] = bf2f((unsigned short)mkv[1]);
            zz[2] = bf2f((unsigned short)mkv[2]);
            zz[3] = bf2f((unsigned short)mkv[3]);
            const int row = kbase + (g & 1) * 4 + (g >> 1) * 32;
            const int fr  = (row & 7) ^ ((row >> 1) & 4);
            const bf16x8 kf0 = *reinterpret_cast<const bf16x8*>(
                KT + row * 128 + ((hi ^ fr) << 4));
            const bf16x8 kf1 = *reinterpret_cast<const bf16x8*>(
                KT + row * 128 + (((4 + hi) ^ fr) << 4));
            __builtin_amdgcn_s_setprio(1);
            zz = __builtin_amdgcn_mfma_f32_16x16x32_bf16(kf0, qa0, zz, 0, 0, 0);
            zz = __builtin_amdgcn_mfma_f32_16x16x32_bf16(kf1, qa1, zz, 0, 0, 0);
            __builtin_amdgcn_s_setprio(0);
            s2[g][0] = zz[0]; s2[g][1] = zz[1]; s2[g][2] = zz[2]; s2[g][3] = zz[3];
        }

        // ---- row max (16 in-reg via max3 tree, then cross-group)
        float tmax;
        {
            const float a = max3f(s2[0][0], s2[0][1], s2[0][2]);
            const float b = max3f(s2[0][3], s2[1][0], s2[1][1]);
            const float c = max3f(s2[1][2], s2[1][3], s2[2][0]);
            const float d = max3f(s2[2][1], s2[2][2], s2[2][3]);
            const float e = max3f(s2[3][0], s2[3][1], s2[3][2]);
            tmax = max3f(max3f(a, b, c), max3f(d, e, s2[3][3]),
                         __builtin_bit_cast(float, 0xff800000u));
        }
        tmax = fmaxf(tmax, __shfl_xor(tmax, 16));
        tmax = fmaxf(tmax, __shfl_xor(tmax, 32));

        // ---- defer-max rescale (THR=8)
        if (__ballot(tmax > m_r + 8.f)) {
            const float newm = fmaxf(m_r, tmax);
            const float sc = exp2f(fmaxf(m_r - newm, -128.f));
            ls *= sc;
#pragma unroll
            for (int c = 0; c < 4; ++c) oAcc[c] *= sc;
            m_r = newm;
        }

        // ---- P = exp2(s2 - m): directly the PV B-fragments (zero shuffle)
        float e_[4][4];
#pragma unroll
        for (int g = 0; g < 4; ++g) {
#pragma unroll
            for (int r = 0; r < 4; ++r) {
                e_[g][r] = exp2f(s2[g][r] - m_r);
                ls += e_[g][r];
            }
        }
        union { unsigned u[4]; bf16x8 v; } P0, P1;
        P0.u[0] = cvtpk(e_[0][0], e_[0][1]); P0.u[1] = cvtpk(e_[0][2], e_[0][3]);
        P0.u[2] = cvtpk(e_[1][0], e_[1][1]); P0.u[3] = cvtpk(e_[1][2], e_[1][3]);
        P1.u[0] = cvtpk(e_[2][0], e_[2][1]); P1.u[1] = cvtpk(e_[2][2], e_[2][3]);
        P1.u[2] = cvtpk(e_[3][0], e_[3][1]); P1.u[3] = cvtpk(e_[3][2], e_[3][3]);

        // ---- PV: O^T[d][q] += V^T . P^T
        const char* VT = lds + 16384 + (t & 1) * 8192;
#pragma unroll
        for (int dg = 0; dg < 4; ++dg) {
            const int rb = (dg * 16 + lr) * 128;
            const bf16x8 v0 = *reinterpret_cast<const bf16x8*>(VT + rb + ((hi ^ fv) << 4));
            const bf16x8 v1 = *reinterpret_cast<const bf16x8*>(VT + rb + (((4 + hi) ^ fv) << 4));
            __builtin_amdgcn_s_setprio(1);
            oAcc[dg] = __builtin_amdgcn_mfma_f32_16x16x32_bf16(v0, P0.v, oAcc[dg], 0, 0, 0);
            oAcc[dg] = __builtin_amdgcn_mfma_f32_16x16x32_bf16(v1, P1.v, oAcc[dg], 0, 0, 0);
            __builtin_amdgcn_s_setprio(0);
        }
    }

    // ---- finalize
    float lt = ls;
    lt += __shfl_xor(lt, 16);
    lt += __shfl_xor(lt, 32);
    const float rl = 1.0f / lt;
    float* ob = out + (size_t)(q0 + lr) * HID + h * HDIM + hi * 4;
#pragma unroll
    for (int dg = 0; dg < 4; ++dg)
        *reinterpret_cast<f32x4*>(ob + dg * 16) = oAcc[dg] * rl;
}

// ---------------------------------------------------------------------------
extern "C" void kernel_launch(void* const* d_in, const int* in_sizes, int n_in,
                              void* d_out, int out_size, void* d_ws, size_t ws_size,
                              hipStream_t stream) {
    const float* hs   = (const float*)d_in[0];
    const float* mask = (const float*)d_in[1];
    const float* Wq   = (const float*)d_in[2];
    const float* bq   = (const float*)d_in[3];
    const float* Wk   = (const float*)d_in[4];
    const float* bk   = (const float*)d_in[5];
    const float* Wv   = (const float*)d_in[6];
    const float* bv   = (const float*)d_in[7];

    short* Qb = (short*)d_ws;                       // bf16 [SEQ][HID], pre-scaled
    short* Kb = Qb + (size_t)SEQ * HID;             // bf16 [SEQ][HID]
    short* Vt = Kb + (size_t)SEQ * HID;             // bf16 [HID][SEQ]
    float* out = (float*)d_out;

    // bf16 scratch carved from d_out (attn overwrites it at the very end)
    short* hsb = (short*)d_out;
    short* Wb  = hsb + (size_t)SEQ * HID;

    cast_bf16_kernel<<<dim3(SEQ * HID / 2048), 256, 0, stream>>>(hs, hsb);
    cast_w_kernel<<<dim3(HID * HID / 2048, 3), 256, 0, stream>>>(Wq, Wk, Wv, Wb);

    qkv_proj_kernel<<<dim3(HID / 128, SEQ / 128, 3), 256, 0, stream>>>(
        hsb, Wb, bq, bk, bv, Qb, Kb, Vt);

    attn_kernel<<<dim3(SEQ / KVB, NHEAD), 256, 0, stream>>>(Qb, Kb, Vt, mask, out);
}

// Round 5
// 148.538 us; speedup vs baseline: 3.6680x; 1.0223x over previous
//
#include <hip/hip_runtime.h>
#include <hip/hip_bf16.h>

#define SEQ 4096
#define HID 768
#define NHEAD 12
#define HDIM 64
#define KVB 64
#define NT (SEQ / KVB)   // 64
#define PBK 64
#define PNT (HID / PBK)  // 12

typedef __attribute__((ext_vector_type(8))) short bf16x8;
typedef __attribute__((ext_vector_type(4))) float f32x4;
typedef __attribute__((ext_vector_type(4))) short s16x4;

static __device__ __forceinline__ short f2bf(float f) {
    unsigned u = __builtin_bit_cast(unsigned, f);
    unsigned r = (u + 0x7fffu + ((u >> 16) & 1u)) >> 16;
    return (short)r;
}
static __device__ __forceinline__ unsigned cvtpk(float lo, float hi) {
    unsigned r;
    asm("v_cvt_pk_bf16_f32 %0, %1, %2" : "=v"(r) : "v"(lo), "v"(hi));
    return r;
}
static __device__ __forceinline__ float max3f(float a, float b, float c) {
    float r;
    asm("v_max3_f32 %0, %1, %2, %3" : "=v"(r) : "v"(a), "v"(b), "v"(c));
    return r;
}
static __device__ __forceinline__ void glds16(const void* g, void* l) {
    __builtin_amdgcn_global_load_lds(
        (const __attribute__((address_space(1))) unsigned*)g,
        (__attribute__((address_space(3))) unsigned*)l, 16, 0, 0);
}

// ---------------------------------------------------------------------------
// fp32 -> bf16 casts
// ---------------------------------------------------------------------------
__global__ __launch_bounds__(256) void cast_bf16_kernel(
    const float* __restrict__ src, short* __restrict__ dst)
{
    const size_t i = (size_t)blockIdx.x * 256 + threadIdx.x;
    const float4* s = reinterpret_cast<const float4*>(src) + i * 2;
    const float4 a = s[0], b = s[1];
    bf16x8 o;
    o[0] = f2bf(a.x); o[1] = f2bf(a.y); o[2] = f2bf(a.z); o[3] = f2bf(a.w);
    o[4] = f2bf(b.x); o[5] = f2bf(b.y); o[6] = f2bf(b.z); o[7] = f2bf(b.w);
    reinterpret_cast<bf16x8*>(dst)[i] = o;
}

__global__ __launch_bounds__(256) void cast_w_kernel(
    const float* __restrict__ Wq, const float* __restrict__ Wk,
    const float* __restrict__ Wv, short* __restrict__ dst)
{
    const int z = blockIdx.y;
    const float* src = (z == 0) ? Wq : ((z == 1) ? Wk : Wv);
    const size_t i = (size_t)blockIdx.x * 256 + threadIdx.x;
    const float4* s = reinterpret_cast<const float4*>(src) + i * 2;
    const float4 a = s[0], b = s[1];
    bf16x8 o;
    o[0] = f2bf(a.x); o[1] = f2bf(a.y); o[2] = f2bf(a.z); o[3] = f2bf(a.w);
    o[4] = f2bf(b.x); o[5] = f2bf(b.y); o[6] = f2bf(b.z); o[7] = f2bf(b.w);
    reinterpret_cast<bf16x8*>(dst + (size_t)z * HID * HID)[i] = o;
}

// ---------------------------------------------------------------------------
// QKV projection, LDS-staged. Tile 128x128, BK=64, dbuf 64KB.
// Q output pre-scaled by 0.125*log2e (folds the softmax scale).
// ---------------------------------------------------------------------------
__global__ __launch_bounds__(256) void qkv_proj_kernel(
    const short* __restrict__ hsb, const short* __restrict__ Wb,
    const float* __restrict__ bq, const float* __restrict__ bk,
    const float* __restrict__ bv,
    short* __restrict__ Qb, short* __restrict__ Kb, short* __restrict__ Vt)
{
    __shared__ __align__(16) char lds[65536];
    const int z = blockIdx.z;
    const float* bias = (z == 0) ? bq : ((z == 1) ? bk : bv);

    const int lane = threadIdx.x & 63;
    const int w    = threadIdx.x >> 6;
    const int lr = lane & 15, hi = lane >> 4;
    const int wi = w >> 1, wj = w & 1;

    const short* Ag; const short* Bg; int ar0, br0;
    if (z < 2) { Ag = Wb + (size_t)z * HID * HID; ar0 = blockIdx.x * 128;
                 Bg = hsb;                        br0 = blockIdx.y * 128; }
    else       { Ag = hsb;                        ar0 = blockIdx.y * 128;
                 Bg = Wb + (size_t)2 * HID * HID; br0 = blockIdx.x * 128; }

    const int rsub = lane >> 3;
    const int c16  = (lane & 7) ^ rsub;

    auto stage = [&](int t, int buf) {
        const int k0 = t * PBK;
#pragma unroll
        for (int c = 0; c < 4; ++c) {
            const int ch = w * 4 + c;
            const int row = ch * 8 + rsub;
            glds16(Ag + (size_t)(ar0 + row) * HID + k0 + c16 * 8,
                   lds + buf * 16384 + ch * 1024);
            glds16(Bg + (size_t)(br0 + row) * HID + k0 + c16 * 8,
                   lds + 32768 + buf * 16384 + ch * 1024);
        }
    };

    stage(0, 0);
    f32x4 acc[4][4] = {};

    for (int t = 0; t < PNT; ++t) {
        asm volatile("s_waitcnt vmcnt(0)" ::: "memory");
        __builtin_amdgcn_s_barrier();
        __builtin_amdgcn_sched_barrier(0);
        if (t + 1 < PNT) stage(t + 1, (t + 1) & 1);
        const char* LA = lds + (t & 1) * 16384;
        const char* LB = lds + 32768 + (t & 1) * 16384;
#pragma unroll
        for (int ks = 0; ks < 2; ++ks) {
            bf16x8 af[4], bf_[4];
#pragma unroll
            for (int i = 0; i < 4; ++i) {
                const int rowA = wi * 64 + i * 16 + lr;
                af[i] = *reinterpret_cast<const bf16x8*>(
                    LA + rowA * 128 + (((ks * 4 + hi) ^ (rowA & 7)) << 4));
                const int rowB = wj * 64 + i * 16 + lr;
                bf_[i] = *reinterpret_cast<const bf16x8*>(
                    LB + rowB * 128 + (((ks * 4 + hi) ^ (rowB & 7)) << 4));
            }
            __builtin_amdgcn_s_setprio(1);
#pragma unroll
            for (int ia = 0; ia < 4; ++ia)
#pragma unroll
                for (int ib = 0; ib < 4; ++ib)
                    acc[ia][ib] = __builtin_amdgcn_mfma_f32_16x16x32_bf16(
                        af[ia], bf_[ib], acc[ia][ib], 0, 0, 0);
            __builtin_amdgcn_s_setprio(0);
        }
    }

    const float SCQ = 0.125f * 1.44269504088896340736f;
    if (z < 2) {
        short* outp = (z == 0) ? Qb : Kb;
        const float sc = (z == 0) ? SCQ : 1.0f;
#pragma unroll
        for (int ia = 0; ia < 4; ++ia) {
            const int nb = ar0 + wi * 64 + ia * 16 + hi * 4;
            const float4 b4 = *reinterpret_cast<const float4*>(bias + nb);
#pragma unroll
            for (int ib = 0; ib < 4; ++ib) {
                const int m = br0 + wj * 64 + ib * 16 + lr;
                s16x4 v;
                v[0] = f2bf((acc[ia][ib][0] + b4.x) * sc);
                v[1] = f2bf((acc[ia][ib][1] + b4.y) * sc);
                v[2] = f2bf((acc[ia][ib][2] + b4.z) * sc);
                v[3] = f2bf((acc[ia][ib][3] + b4.w) * sc);
                *reinterpret_cast<s16x4*>(outp + (size_t)m * HID + nb) = v;
            }
        }
    } else {
#pragma unroll
        for (int ib = 0; ib < 4; ++ib) {
            const int n = br0 + wj * 64 + ib * 16 + lr;
            const float bb = bias[n];
#pragma unroll
            for (int ia = 0; ia < 4; ++ia) {
                const int mb = ar0 + wi * 64 + ia * 16 + hi * 4;
                s16x4 v;
                v[0] = f2bf(acc[ia][ib][0] + bb);
                v[1] = f2bf(acc[ia][ib][1] + bb);
                v[2] = f2bf(acc[ia][ib][2] + bb);
                v[3] = f2bf(acc[ia][ib][3] + bb);
                *reinterpret_cast<s16x4*>(Vt + (size_t)n * SEQ + mb) = v;
            }
        }
    }
}

// ---------------------------------------------------------------------------
// Flash attention: 4 waves = 2(q-half) x 2(key-half); each wave 32q x 32k
// per tile (2x the LDS-read reuse vs 16q x 64k). Key-halves run independent
// online softmax (m,l,O per wave) and flash-merge once at kernel end via LDS.
// Zero-shuffle P: MFMA kg computes keys hi*8+kg*4+r -> lane's 16 scores are
// exactly its PV B-fragment. Mask staged as f32*log2e, used as MFMA C-init
// (broadcast read, no VALU convert).
// LDS: K dbuf 2x8KB @0, V dbuf 2x8KB @16384, mask f32 16KB @32768. 48KB.
// ---------------------------------------------------------------------------
__global__ __launch_bounds__(256, 3) void attn_kernel(
    const short* __restrict__ Qb, const short* __restrict__ Kb,
    const short* __restrict__ Vt, const float* __restrict__ maskp,
    float* __restrict__ out)
{
    __shared__ __align__(16) char lds[49152];
    const int tid  = threadIdx.x;
    const int lane = tid & 63;
    const int w    = tid >> 6;
    const int lr = lane & 15, hi = lane >> 4;
    const int qh = w >> 1, kh = w & 1;       // wave = (q-half, key-half)
    const int h  = blockIdx.y;
    const int q0 = blockIdx.x * 64 + qh * 32;
    const float ML = 1.44269504088896340736f;

    const int srow = lane >> 3;
    auto stage = [&](int t, int buf) {
        const int kt = t * KVB;
#pragma unroll
        for (int j = 0; j < 2; ++j) {
            const int ch  = w * 2 + j;
            const int row = ch * 8 + srow;
            const int c16 = (lane & 7) ^ srow ^ ((ch & 1) << 2);
            glds16(Kb + (size_t)(kt + row) * HID + h * HDIM + c16 * 8,
                   lds + buf * 8192 + ch * 1024);
            glds16(Vt + (size_t)(h * HDIM + row) * SEQ + kt + c16 * 8,
                   lds + 16384 + buf * 8192 + ch * 1024);
        }
    };

    stage(0, 0);   // in flight across mask/Q staging

    // stage mask*log2e as f32 (once)
    {
        float* mb = (float*)(lds + 32768);
        const int base = tid * 16;
#pragma unroll
        for (int i = 0; i < 4; ++i) {
            float4 m4 = *reinterpret_cast<const float4*>(maskp + base + i * 4);
            m4.x *= ML; m4.y *= ML; m4.z *= ML; m4.w *= ML;
            *reinterpret_cast<float4*>(mb + base + i * 4) = m4;
        }
    }

    // Q fragments [qg][ks]: Q[q0+qg*16+lr][ks*32 + hi*8 ..+7] (pre-scaled)
    const short* qbase = Qb + (size_t)(q0 + lr) * HID + h * HDIM + hi * 8;
    bf16x8 qf[2][2];
    qf[0][0] = *reinterpret_cast<const bf16x8*>(qbase);
    qf[0][1] = *reinterpret_cast<const bf16x8*>(qbase + 32);
    qf[1][0] = *reinterpret_cast<const bf16x8*>(qbase + 16 * HID);
    qf[1][1] = *reinterpret_cast<const bf16x8*>(qbase + 16 * HID + 32);

    __syncthreads();   // mask visible; stage(0) also drained

    f32x4 acc[4][2] = {};                     // [dg][qg]
    float m_r[2] = {-INFINITY, -INFINITY};
    float ls[2]  = {0.f, 0.f};
    const int kbase = ((lr >> 2) * 8) + (lr & 3) + kh * 32;  // key-permutation
    const int fv    = (lr & 7) ^ (((lr >> 3) & 1) << 2);     // V-row swizzle
    const int vslot = ((kh * 4 + hi) ^ fv) << 4;

    for (int t = 0; t < NT; ++t) {
        asm volatile("s_waitcnt vmcnt(0)" ::: "memory");  // stage(t) landed
        __builtin_amdgcn_s_barrier();
        __builtin_amdgcn_sched_barrier(0);
        if (t + 1 < NT) stage(t + 1, (t + 1) & 1);

        // ---- QK^T, key-permuted: MFMA kg -> keys kh*32 + hi*8 + kg*4 + r,
        //      q = qg*16 + lr. C-init = mask*log2e (broadcast f32x4).
        const char* KT = lds + (t & 1) * 8192;
        const float* mk = (const float*)(lds + 32768) + t * KVB + kh * 32 + hi * 8;
        float s2[2][2][4];
#pragma unroll
        for (int kg = 0; kg < 2; ++kg) {
            const int row = kbase + kg * 4;
            const int fr  = (row & 7) ^ ((row >> 1) & 4);
            const bf16x8 kf0 = *reinterpret_cast<const bf16x8*>(
                KT + row * 128 + ((hi ^ fr) << 4));
            const bf16x8 kf1 = *reinterpret_cast<const bf16x8*>(
                KT + row * 128 + (((4 + hi) ^ fr) << 4));
            const f32x4 ci = *reinterpret_cast<const f32x4*>(mk + kg * 4);
            __builtin_amdgcn_s_setprio(1);
#pragma unroll
            for (int qg = 0; qg < 2; ++qg) {
                f32x4 zz = ci;
                zz = __builtin_amdgcn_mfma_f32_16x16x32_bf16(kf0, qf[qg][0], zz, 0, 0, 0);
                zz = __builtin_amdgcn_mfma_f32_16x16x32_bf16(kf1, qf[qg][1], zz, 0, 0, 0);
                s2[kg][qg][0] = zz[0]; s2[kg][qg][1] = zz[1];
                s2[kg][qg][2] = zz[2]; s2[kg][qg][3] = zz[3];
            }
            __builtin_amdgcn_s_setprio(0);
        }

        // ---- per-qg row max over this wave's 32 keys
        float tmax[2];
#pragma unroll
        for (int qg = 0; qg < 2; ++qg) {
            const float a = max3f(s2[0][qg][0], s2[0][qg][1], s2[0][qg][2]);
            const float b = max3f(s2[0][qg][3], s2[1][qg][0], s2[1][qg][1]);
            const float c = max3f(s2[1][qg][2], s2[1][qg][3], a);
            float t_ = fmaxf(b, c);
            t_ = fmaxf(t_, __shfl_xor(t_, 16));
            t_ = fmaxf(t_, __shfl_xor(t_, 32));
            tmax[qg] = t_;
        }

        // ---- defer-max rescale (THR=8)
        const bool need = (tmax[0] > m_r[0] + 8.f) || (tmax[1] > m_r[1] + 8.f);
        if (__ballot(need)) {
#pragma unroll
            for (int qg = 0; qg < 2; ++qg) {
                const float newm = fmaxf(m_r[qg], tmax[qg]);
                const float sc = exp2f(fmaxf(m_r[qg] - newm, -128.f));
                ls[qg] *= sc;
#pragma unroll
                for (int dg = 0; dg < 4; ++dg) acc[dg][qg] *= sc;
                m_r[qg] = newm;
            }
        }

        // ---- P = exp2(s2 - m): keys hi*8+kg*4+r are exactly the PV B-frag
        union { unsigned u[4]; bf16x8 v; } P[2];
#pragma unroll
        for (int qg = 0; qg < 2; ++qg) {
            float e0 = exp2f(s2[0][qg][0] - m_r[qg]);
            float e1 = exp2f(s2[0][qg][1] - m_r[qg]);
            float e2 = exp2f(s2[0][qg][2] - m_r[qg]);
            float e3 = exp2f(s2[0][qg][3] - m_r[qg]);
            float e4 = exp2f(s2[1][qg][0] - m_r[qg]);
            float e5 = exp2f(s2[1][qg][1] - m_r[qg]);
            float e6 = exp2f(s2[1][qg][2] - m_r[qg]);
            float e7 = exp2f(s2[1][qg][3] - m_r[qg]);
            ls[qg] += ((e0 + e1) + (e2 + e3)) + ((e4 + e5) + (e6 + e7));
            P[qg].u[0] = cvtpk(e0, e1); P[qg].u[1] = cvtpk(e2, e3);
            P[qg].u[2] = cvtpk(e4, e5); P[qg].u[3] = cvtpk(e6, e7);
        }

        // ---- PV: O[d][q] += V[d][k]·P[k][q] over this wave's 32 keys
        const char* VT = lds + 16384 + (t & 1) * 8192;
#pragma unroll
        for (int dg = 0; dg < 4; ++dg) {
            const bf16x8 vf = *reinterpret_cast<const bf16x8*>(
                VT + (dg * 16 + lr) * 128 + vslot);
            __builtin_amdgcn_s_setprio(1);
            acc[dg][0] = __builtin_amdgcn_mfma_f32_16x16x32_bf16(vf, P[0].v, acc[dg][0], 0, 0, 0);
            acc[dg][1] = __builtin_amdgcn_mfma_f32_16x16x32_bf16(vf, P[1].v, acc[dg][1], 0, 0, 0);
            __builtin_amdgcn_s_setprio(0);
        }
    }

    // ---- reduce l across hi-groups (per qg)
#pragma unroll
    for (int qg = 0; qg < 2; ++qg) {
        float t_ = ls[qg];
        t_ += __shfl_xor(t_, 16);
        t_ += __shfl_xor(t_, 32);
        ls[qg] = t_;
    }

    // ---- flash-merge the two key-halves through LDS (reuse K/V buffers)
    __syncthreads();
    float* mg = (float*)lds;                 // [qh][dg*2+qg][lane] f32x4 = 16KB
    float* mlb = (float*)(lds + 16384);      // [qh][qg][lane][2] = 2KB
    if (kh == 1) {
#pragma unroll
        for (int qg = 0; qg < 2; ++qg) {
            float2 v; v.x = m_r[qg]; v.y = ls[qg];
            *reinterpret_cast<float2*>(mlb + (((qh * 2 + qg) * 64 + lane) * 2)) = v;
        }
#pragma unroll
        for (int dg = 0; dg < 4; ++dg)
#pragma unroll
            for (int qg = 0; qg < 2; ++qg)
                *reinterpret_cast<f32x4*>(
                    mg + ((qh * 8 + dg * 2 + qg) * 64 + lane) * 4) = acc[dg][qg];
    }
    __syncthreads();
    if (kh == 0) {
        float sc0[2], sc1[2], rl[2];
#pragma unroll
        for (int qg = 0; qg < 2; ++qg) {
            const float2 v = *reinterpret_cast<const float2*>(
                mlb + (((qh * 2 + qg) * 64 + lane) * 2));
            const float mm = fmaxf(m_r[qg], v.x);
            sc0[qg] = exp2f(m_r[qg] - mm);
            sc1[qg] = exp2f(v.x - mm);
            rl[qg] = 1.0f / (ls[qg] * sc0[qg] + v.y * sc1[qg]);
        }
#pragma unroll
        for (int dg = 0; dg < 4; ++dg) {
#pragma unroll
            for (int qg = 0; qg < 2; ++qg) {
                const f32x4 o1 = *reinterpret_cast<const f32x4*>(
                    mg + ((qh * 8 + dg * 2 + qg) * 64 + lane) * 4);
                const f32x4 of = (acc[dg][qg] * sc0[qg] + o1 * sc1[qg]) * rl[qg];
                float* op = out + (size_t)(q0 + qg * 16 + lr) * HID
                          + h * HDIM + dg * 16 + hi * 4;
                *reinterpret_cast<f32x4*>(op) = of;
            }
        }
    }
}

// ---------------------------------------------------------------------------
extern "C" void kernel_launch(void* const* d_in, const int* in_sizes, int n_in,
                              void* d_out, int out_size, void* d_ws, size_t ws_size,
                              hipStream_t stream) {
    const float* hs   = (const float*)d_in[0];
    const float* mask = (const float*)d_in[1];
    const float* Wq   = (const float*)d_in[2];
    const float* bq   = (const float*)d_in[3];
    const float* Wk   = (const float*)d_in[4];
    const float* bk   = (const float*)d_in[5];
    const float* Wv   = (const float*)d_in[6];
    const float* bv   = (const float*)d_in[7];

    short* Qb = (short*)d_ws;                       // bf16 [SEQ][HID], pre-scaled
    short* Kb = Qb + (size_t)SEQ * HID;             // bf16 [SEQ][HID]
    short* Vt = Kb + (size_t)SEQ * HID;             // bf16 [HID][SEQ]
    float* out = (float*)d_out;

    // bf16 scratch carved from d_out (attn overwrites it at the very end)
    short* hsb = (short*)d_out;
    short* Wb  = hsb + (size_t)SEQ * HID;

    cast_bf16_kernel<<<dim3(SEQ * HID / 2048), 256, 0, stream>>>(hs, hsb);
    cast_w_kernel<<<dim3(HID * HID / 2048, 3), 256, 0, stream>>>(Wq, Wk, Wv, Wb);

    qkv_proj_kernel<<<dim3(HID / 128, SEQ / 128, 3), 256, 0, stream>>>(
        hsb, Wb, bq, bk, bv, Qb, Kb, Vt);

    attn_kernel<<<dim3(SEQ / KVB, NHEAD), 256, 0, stream>>>(Qb, Kb, Vt, mask, out);
}

// Round 6
// 132.579 us; speedup vs baseline: 4.1095x; 1.1204x over previous
//
#include <hip/hip_runtime.h>
#include <hip/hip_bf16.h>

#define SEQ 4096
#define HID 768
#define NHEAD 12
#define HDIM 64
#define KVB 64
#define NT (SEQ / KVB)   // 64
#define PBK 64
#define PNT (HID / PBK)  // 12

typedef __attribute__((ext_vector_type(8))) short bf16x8;
typedef __attribute__((ext_vector_type(4))) float f32x4;
typedef __attribute__((ext_vector_type(4))) short s16x4;

static __device__ __forceinline__ short f2bf(float f) {
    unsigned u = __builtin_bit_cast(unsigned, f);
    unsigned r = (u + 0x7fffu + ((u >> 16) & 1u)) >> 16;
    return (short)r;
}
static __device__ __forceinline__ unsigned cvtpk(float lo, float hi) {
    unsigned r;
    asm("v_cvt_pk_bf16_f32 %0, %1, %2" : "=v"(r) : "v"(lo), "v"(hi));
    return r;
}
static __device__ __forceinline__ float max3f(float a, float b, float c) {
    float r;
    asm("v_max3_f32 %0, %1, %2, %3" : "=v"(r) : "v"(a), "v"(b), "v"(c));
    return r;
}
static __device__ __forceinline__ void glds16(const void* g, void* l) {
    __builtin_amdgcn_global_load_lds(
        (const __attribute__((address_space(1))) unsigned*)g,
        (__attribute__((address_space(3))) unsigned*)l, 16, 0, 0);
}

// ---------------------------------------------------------------------------
// fp32 -> bf16 casts
// ---------------------------------------------------------------------------
__global__ __launch_bounds__(256) void cast_bf16_kernel(
    const float* __restrict__ src, short* __restrict__ dst)
{
    const size_t i = (size_t)blockIdx.x * 256 + threadIdx.x;
    const float4* s = reinterpret_cast<const float4*>(src) + i * 2;
    const float4 a = s[0], b = s[1];
    bf16x8 o;
    o[0] = f2bf(a.x); o[1] = f2bf(a.y); o[2] = f2bf(a.z); o[3] = f2bf(a.w);
    o[4] = f2bf(b.x); o[5] = f2bf(b.y); o[6] = f2bf(b.z); o[7] = f2bf(b.w);
    reinterpret_cast<bf16x8*>(dst)[i] = o;
}

__global__ __launch_bounds__(256) void cast_w_kernel(
    const float* __restrict__ Wq, const float* __restrict__ Wk,
    const float* __restrict__ Wv, short* __restrict__ dst)
{
    const int z = blockIdx.y;
    const float* src = (z == 0) ? Wq : ((z == 1) ? Wk : Wv);
    const size_t i = (size_t)blockIdx.x * 256 + threadIdx.x;
    const float4* s = reinterpret_cast<const float4*>(src) + i * 2;
    const float4 a = s[0], b = s[1];
    bf16x8 o;
    o[0] = f2bf(a.x); o[1] = f2bf(a.y); o[2] = f2bf(a.z); o[3] = f2bf(a.w);
    o[4] = f2bf(b.x); o[5] = f2bf(b.y); o[6] = f2bf(b.z); o[7] = f2bf(b.w);
    reinterpret_cast<bf16x8*>(dst + (size_t)z * HID * HID)[i] = o;
}

// ---------------------------------------------------------------------------
// QKV projection, LDS-staged. Tile 128x128, BK=64, dbuf 64KB.
// Q output pre-scaled by 0.125*log2e (folds the softmax scale).
// ---------------------------------------------------------------------------
__global__ __launch_bounds__(256) void qkv_proj_kernel(
    const short* __restrict__ hsb, const short* __restrict__ Wb,
    const float* __restrict__ bq, const float* __restrict__ bk,
    const float* __restrict__ bv,
    short* __restrict__ Qb, short* __restrict__ Kb, short* __restrict__ Vt)
{
    __shared__ __align__(16) char lds[65536];
    const int z = blockIdx.z;
    const float* bias = (z == 0) ? bq : ((z == 1) ? bk : bv);

    const int lane = threadIdx.x & 63;
    const int w    = threadIdx.x >> 6;
    const int lr = lane & 15, hi = lane >> 4;
    const int wi = w >> 1, wj = w & 1;

    const short* Ag; const short* Bg; int ar0, br0;
    if (z < 2) { Ag = Wb + (size_t)z * HID * HID; ar0 = blockIdx.x * 128;
                 Bg = hsb;                        br0 = blockIdx.y * 128; }
    else       { Ag = hsb;                        ar0 = blockIdx.y * 128;
                 Bg = Wb + (size_t)2 * HID * HID; br0 = blockIdx.x * 128; }

    const int rsub = lane >> 3;
    const int c16  = (lane & 7) ^ rsub;

    auto stage = [&](int t, int buf) {
        const int k0 = t * PBK;
#pragma unroll
        for (int c = 0; c < 4; ++c) {
            const int ch = w * 4 + c;
            const int row = ch * 8 + rsub;
            glds16(Ag + (size_t)(ar0 + row) * HID + k0 + c16 * 8,
                   lds + buf * 16384 + ch * 1024);
            glds16(Bg + (size_t)(br0 + row) * HID + k0 + c16 * 8,
                   lds + 32768 + buf * 16384 + ch * 1024);
        }
    };

    stage(0, 0);
    f32x4 acc[4][4] = {};

    for (int t = 0; t < PNT; ++t) {
        asm volatile("s_waitcnt vmcnt(0)" ::: "memory");
        __builtin_amdgcn_s_barrier();
        __builtin_amdgcn_sched_barrier(0);
        if (t + 1 < PNT) stage(t + 1, (t + 1) & 1);
        const char* LA = lds + (t & 1) * 16384;
        const char* LB = lds + 32768 + (t & 1) * 16384;
#pragma unroll
        for (int ks = 0; ks < 2; ++ks) {
            bf16x8 af[4], bf_[4];
#pragma unroll
            for (int i = 0; i < 4; ++i) {
                const int rowA = wi * 64 + i * 16 + lr;
                af[i] = *reinterpret_cast<const bf16x8*>(
                    LA + rowA * 128 + (((ks * 4 + hi) ^ (rowA & 7)) << 4));
                const int rowB = wj * 64 + i * 16 + lr;
                bf_[i] = *reinterpret_cast<const bf16x8*>(
                    LB + rowB * 128 + (((ks * 4 + hi) ^ (rowB & 7)) << 4));
            }
            __builtin_amdgcn_s_setprio(1);
#pragma unroll
            for (int ia = 0; ia < 4; ++ia)
#pragma unroll
                for (int ib = 0; ib < 4; ++ib)
                    acc[ia][ib] = __builtin_amdgcn_mfma_f32_16x16x32_bf16(
                        af[ia], bf_[ib], acc[ia][ib], 0, 0, 0);
            __builtin_amdgcn_s_setprio(0);
        }
    }

    const float SCQ = 0.125f * 1.44269504088896340736f;
    if (z < 2) {
        short* outp = (z == 0) ? Qb : Kb;
        const float sc = (z == 0) ? SCQ : 1.0f;
#pragma unroll
        for (int ia = 0; ia < 4; ++ia) {
            const int nb = ar0 + wi * 64 + ia * 16 + hi * 4;
            const float4 b4 = *reinterpret_cast<const float4*>(bias + nb);
#pragma unroll
            for (int ib = 0; ib < 4; ++ib) {
                const int m = br0 + wj * 64 + ib * 16 + lr;
                s16x4 v;
                v[0] = f2bf((acc[ia][ib][0] + b4.x) * sc);
                v[1] = f2bf((acc[ia][ib][1] + b4.y) * sc);
                v[2] = f2bf((acc[ia][ib][2] + b4.z) * sc);
                v[3] = f2bf((acc[ia][ib][3] + b4.w) * sc);
                *reinterpret_cast<s16x4*>(outp + (size_t)m * HID + nb) = v;
            }
        }
    } else {
#pragma unroll
        for (int ib = 0; ib < 4; ++ib) {
            const int n = br0 + wj * 64 + ib * 16 + lr;
            const float bb = bias[n];
#pragma unroll
            for (int ia = 0; ia < 4; ++ia) {
                const int mb = ar0 + wi * 64 + ia * 16 + hi * 4;
                s16x4 v;
                v[0] = f2bf(acc[ia][ib][0] + bb);
                v[1] = f2bf(acc[ia][ib][1] + bb);
                v[2] = f2bf(acc[ia][ib][2] + bb);
                v[3] = f2bf(acc[ia][ib][3] + bb);
                *reinterpret_cast<s16x4*>(Vt + (size_t)n * SEQ + mb) = v;
            }
        }
    }
}

// ---------------------------------------------------------------------------
// Flash attention: 4 waves = 2(q-half) x 2(key-half); each wave 32q x 32k.
// Per-lane deferred-max softmax: common path has ZERO cross-lane ops —
// e = exp2(s2 - m); violation (any e > 256 <=> s - m > 8) detected by a
// per-lane max3 tree + one ballot; rare recovery path does the full
// cross-lane reduce + rescale + recompute. m bootstraps via t=0 violation.
// Zero-shuffle P (key-permuted QK^T); mask*log2e staged f32 as MFMA C-init.
// LDS: K dbuf 2x8KB @0, V dbuf 2x8KB @16384, mask f32 16KB @32768. 48KB.
// ---------------------------------------------------------------------------
__global__ __launch_bounds__(256, 3) void attn_kernel(
    const short* __restrict__ Qb, const short* __restrict__ Kb,
    const short* __restrict__ Vt, const float* __restrict__ maskp,
    float* __restrict__ out)
{
    __shared__ __align__(16) char lds[49152];
    const int tid  = threadIdx.x;
    const int lane = tid & 63;
    const int w    = tid >> 6;
    const int lr = lane & 15, hi = lane >> 4;
    const int qh = w >> 1, kh = w & 1;       // wave = (q-half, key-half)
    const int h  = blockIdx.y;
    const int q0 = blockIdx.x * 64 + qh * 32;
    const float ML = 1.44269504088896340736f;

    const int srow = lane >> 3;
    auto stage = [&](int t, int buf) {
        const int kt = t * KVB;
#pragma unroll
        for (int j = 0; j < 2; ++j) {
            const int ch  = w * 2 + j;
            const int row = ch * 8 + srow;
            const int c16 = (lane & 7) ^ srow ^ ((ch & 1) << 2);
            glds16(Kb + (size_t)(kt + row) * HID + h * HDIM + c16 * 8,
                   lds + buf * 8192 + ch * 1024);
            glds16(Vt + (size_t)(h * HDIM + row) * SEQ + kt + c16 * 8,
                   lds + 16384 + buf * 8192 + ch * 1024);
        }
    };

    stage(0, 0);   // in flight across mask/Q staging

    // stage mask*log2e as f32 (once)
    {
        float* mb = (float*)(lds + 32768);
        const int base = tid * 16;
#pragma unroll
        for (int i = 0; i < 4; ++i) {
            float4 m4 = *reinterpret_cast<const float4*>(maskp + base + i * 4);
            m4.x *= ML; m4.y *= ML; m4.z *= ML; m4.w *= ML;
            *reinterpret_cast<float4*>(mb + base + i * 4) = m4;
        }
    }

    // Q fragments [qg][ks]: Q[q0+qg*16+lr][ks*32 + hi*8 ..+7] (pre-scaled)
    const short* qbase = Qb + (size_t)(q0 + lr) * HID + h * HDIM + hi * 8;
    bf16x8 qf[2][2];
    qf[0][0] = *reinterpret_cast<const bf16x8*>(qbase);
    qf[0][1] = *reinterpret_cast<const bf16x8*>(qbase + 32);
    qf[1][0] = *reinterpret_cast<const bf16x8*>(qbase + 16 * HID);
    qf[1][1] = *reinterpret_cast<const bf16x8*>(qbase + 16 * HID + 32);

    __syncthreads();   // mask visible; stage(0) also drained

    f32x4 acc[4][2] = {};                     // [dg][qg]
    float m_r[2] = {-INFINITY, -INFINITY};
    float ls[2]  = {0.f, 0.f};
    const int kbase = ((lr >> 2) * 8) + (lr & 3) + kh * 32;  // key-permutation
    const int fv    = (lr & 7) ^ (((lr >> 3) & 1) << 2);     // V-row swizzle
    const int vslot = ((kh * 4 + hi) ^ fv) << 4;

    for (int t = 0; t < NT; ++t) {
        asm volatile("s_waitcnt vmcnt(0)" ::: "memory");  // stage(t) landed
        __builtin_amdgcn_s_barrier();
        __builtin_amdgcn_sched_barrier(0);
        if (t + 1 < NT) stage(t + 1, (t + 1) & 1);

        // ---- QK^T, key-permuted: MFMA kg -> keys kh*32 + hi*8 + kg*4 + r,
        //      q = qg*16 + lr. C-init = mask*log2e (broadcast f32x4).
        const char* KT = lds + (t & 1) * 8192;
        const float* mk = (const float*)(lds + 32768) + t * KVB + kh * 32 + hi * 8;
        float s2[2][2][4];
#pragma unroll
        for (int kg = 0; kg < 2; ++kg) {
            const int row = kbase + kg * 4;
            const int fr  = (row & 7) ^ ((row >> 1) & 4);
            const bf16x8 kf0 = *reinterpret_cast<const bf16x8*>(
                KT + row * 128 + ((hi ^ fr) << 4));
            const bf16x8 kf1 = *reinterpret_cast<const bf16x8*>(
                KT + row * 128 + (((4 + hi) ^ fr) << 4));
            const f32x4 ci = *reinterpret_cast<const f32x4*>(mk + kg * 4);
            __builtin_amdgcn_s_setprio(1);
#pragma unroll
            for (int qg = 0; qg < 2; ++qg) {
                f32x4 zz = ci;
                zz = __builtin_amdgcn_mfma_f32_16x16x32_bf16(kf0, qf[qg][0], zz, 0, 0, 0);
                zz = __builtin_amdgcn_mfma_f32_16x16x32_bf16(kf1, qf[qg][1], zz, 0, 0, 0);
                s2[kg][qg][0] = zz[0]; s2[kg][qg][1] = zz[1];
                s2[kg][qg][2] = zz[2]; s2[kg][qg][3] = zz[3];
            }
            __builtin_amdgcn_s_setprio(0);
        }

        // ---- e = exp2(s2 - m), per-lane (NO cross-lane ops in common path)
        float e_[2][2][4];
#pragma unroll
        for (int kg = 0; kg < 2; ++kg)
#pragma unroll
            for (int qg = 0; qg < 2; ++qg)
#pragma unroll
                for (int r = 0; r < 4; ++r)
                    e_[kg][qg][r] = exp2f(s2[kg][qg][r] - m_r[qg]);

        // ---- per-lane violation check: any e > 2^8 (<=> s - m > 8)?
        float pmax;
        {
            const float a = max3f(e_[0][0][0], e_[0][0][1], e_[0][0][2]);
            const float b = max3f(e_[0][0][3], e_[0][1][0], e_[0][1][1]);
            const float c = max3f(e_[0][1][2], e_[0][1][3], e_[1][0][0]);
            const float d = max3f(e_[1][0][1], e_[1][0][2], e_[1][0][3]);
            const float f = max3f(e_[1][1][0], e_[1][1][1], e_[1][1][2]);
            pmax = max3f(max3f(a, b, c), max3f(d, f, e_[1][1][3]),
                         __builtin_bit_cast(float, 0x00000000u));
        }
        if (__ballot(pmax > 256.f)) {
            // ---- rare recovery: full cross-lane max, rescale, recompute e
#pragma unroll
            for (int qg = 0; qg < 2; ++qg) {
                float t_ = fmaxf(
                    max3f(s2[0][qg][0], s2[0][qg][1], s2[0][qg][2]),
                    max3f(fmaxf(s2[0][qg][3], s2[1][qg][0]),
                          fmaxf(s2[1][qg][1], s2[1][qg][2]), s2[1][qg][3]));
                t_ = fmaxf(t_, __shfl_xor(t_, 16));
                t_ = fmaxf(t_, __shfl_xor(t_, 32));
                const float newm = fmaxf(m_r[qg], t_);
                const float sc = exp2f(fmaxf(m_r[qg] - newm, -128.f));
                ls[qg] *= sc;
#pragma unroll
                for (int dg = 0; dg < 4; ++dg) acc[dg][qg] *= sc;
                m_r[qg] = newm;
#pragma unroll
                for (int kg = 0; kg < 2; ++kg)
#pragma unroll
                    for (int r = 0; r < 4; ++r)
                        e_[kg][qg][r] = exp2f(s2[kg][qg][r] - newm);
            }
        }

        // ---- accumulate l, pack P (zero-shuffle: e's ARE the PV B-frag)
        union { unsigned u[4]; bf16x8 v; } P[2];
#pragma unroll
        for (int qg = 0; qg < 2; ++qg) {
            ls[qg] += ((e_[0][qg][0] + e_[0][qg][1]) + (e_[0][qg][2] + e_[0][qg][3]))
                    + ((e_[1][qg][0] + e_[1][qg][1]) + (e_[1][qg][2] + e_[1][qg][3]));
            P[qg].u[0] = cvtpk(e_[0][qg][0], e_[0][qg][1]);
            P[qg].u[1] = cvtpk(e_[0][qg][2], e_[0][qg][3]);
            P[qg].u[2] = cvtpk(e_[1][qg][0], e_[1][qg][1]);
            P[qg].u[3] = cvtpk(e_[1][qg][2], e_[1][qg][3]);
        }

        // ---- PV: O[d][q] += V[d][k]·P[k][q] over this wave's 32 keys
        const char* VT = lds + 16384 + (t & 1) * 8192;
#pragma unroll
        for (int dg = 0; dg < 4; ++dg) {
            const bf16x8 vf = *reinterpret_cast<const bf16x8*>(
                VT + (dg * 16 + lr) * 128 + vslot);
            __builtin_amdgcn_s_setprio(1);
            acc[dg][0] = __builtin_amdgcn_mfma_f32_16x16x32_bf16(vf, P[0].v, acc[dg][0], 0, 0, 0);
            acc[dg][1] = __builtin_amdgcn_mfma_f32_16x16x32_bf16(vf, P[1].v, acc[dg][1], 0, 0, 0);
            __builtin_amdgcn_s_setprio(0);
        }
    }

    // ---- reduce l across hi-groups (per qg)
#pragma unroll
    for (int qg = 0; qg < 2; ++qg) {
        float t_ = ls[qg];
        t_ += __shfl_xor(t_, 16);
        t_ += __shfl_xor(t_, 32);
        ls[qg] = t_;
    }

    // ---- flash-merge the two key-halves through LDS (reuse K/V buffers)
    __syncthreads();
    float* mg = (float*)lds;                 // [qh][dg*2+qg][lane] f32x4 = 16KB
    float* mlb = (float*)(lds + 16384);      // [qh][qg][lane][2] = 2KB
    if (kh == 1) {
#pragma unroll
        for (int qg = 0; qg < 2; ++qg) {
            float2 v; v.x = m_r[qg]; v.y = ls[qg];
            *reinterpret_cast<float2*>(mlb + (((qh * 2 + qg) * 64 + lane) * 2)) = v;
        }
#pragma unroll
        for (int dg = 0; dg < 4; ++dg)
#pragma unroll
            for (int qg = 0; qg < 2; ++qg)
                *reinterpret_cast<f32x4*>(
                    mg + ((qh * 8 + dg * 2 + qg) * 64 + lane) * 4) = acc[dg][qg];
    }
    __syncthreads();
    if (kh == 0) {
        float sc0[2], sc1[2], rl[2];
#pragma unroll
        for (int qg = 0; qg < 2; ++qg) {
            const float2 v = *reinterpret_cast<const float2*>(
                mlb + (((qh * 2 + qg) * 64 + lane) * 2));
            const float mm = fmaxf(m_r[qg], v.x);
            sc0[qg] = exp2f(fmaxf(m_r[qg] - mm, -128.f));
            sc1[qg] = exp2f(fmaxf(v.x - mm, -128.f));
            rl[qg] = 1.0f / (ls[qg] * sc0[qg] + v.y * sc1[qg]);
        }
#pragma unroll
        for (int dg = 0; dg < 4; ++dg) {
#pragma unroll
            for (int qg = 0; qg < 2; ++qg) {
                const f32x4 o1 = *reinterpret_cast<const f32x4*>(
                    mg + ((qh * 8 + dg * 2 + qg) * 64 + lane) * 4);
                const f32x4 of = (acc[dg][qg] * sc0[qg] + o1 * sc1[qg]) * rl[qg];
                float* op = out + (size_t)(q0 + qg * 16 + lr) * HID
                          + h * HDIM + dg * 16 + hi * 4;
                *reinterpret_cast<f32x4*>(op) = of;
            }
        }
    }
}

// ---------------------------------------------------------------------------
extern "C" void kernel_launch(void* const* d_in, const int* in_sizes, int n_in,
                              void* d_out, int out_size, void* d_ws, size_t ws_size,
                              hipStream_t stream) {
    const float* hs   = (const float*)d_in[0];
    const float* mask = (const float*)d_in[1];
    const float* Wq   = (const float*)d_in[2];
    const float* bq   = (const float*)d_in[3];
    const float* Wk   = (const float*)d_in[4];
    const float* bk   = (const float*)d_in[5];
    const float* Wv   = (const float*)d_in[6];
    const float* bv   = (const float*)d_in[7];

    short* Qb = (short*)d_ws;                       // bf16 [SEQ][HID], pre-scaled
    short* Kb = Qb + (size_t)SEQ * HID;             // bf16 [SEQ][HID]
    short* Vt = Kb + (size_t)SEQ * HID;             // bf16 [HID][SEQ]
    float* out = (float*)d_out;

    // bf16 scratch carved from d_out (attn overwrites it at the very end)
    short* hsb = (short*)d_out;
    short* Wb  = hsb + (size_t)SEQ * HID;

    cast_bf16_kernel<<<dim3(SEQ * HID / 2048), 256, 0, stream>>>(hs, hsb);
    cast_w_kernel<<<dim3(HID * HID / 2048, 3), 256, 0, stream>>>(Wq, Wk, Wv, Wb);

    qkv_proj_kernel<<<dim3(HID / 128, SEQ / 128, 3), 256, 0, stream>>>(
        hsb, Wb, bq, bk, bv, Qb, Kb, Vt);

    attn_kernel<<<dim3(SEQ / KVB, NHEAD), 256, 0, stream>>>(Qb, Kb, Vt, mask, out);
}